// Round 1
// baseline (1057.969 us; speedup 1.0000x reference)
//
#include <hip/hip_runtime.h>
#include <stdint.h>

typedef __attribute__((ext_vector_type(4))) float f32x4;
typedef __attribute__((ext_vector_type(4))) unsigned int u32x4;
typedef __attribute__((ext_vector_type(8))) short bf16x8;

#define HDIM 1024
#define EDIM 1024
#define BDIM 128
#define VDIM 40000
#define LDIM 256
#define SDIM 10
#define BV (128*40000)

__device__ __forceinline__ unsigned rne_bf16(float f) {
    unsigned x = __float_as_uint(f);
    return ((x + 0x7FFFu + ((x >> 16) & 1u)) >> 16) & 0xFFFFu;
}
__device__ __forceinline__ unsigned pack2(float a, float b) {
    return rne_bf16(a) | (rne_bf16(b) << 16);
}
__device__ __forceinline__ float sigm(float x) { return 1.0f / (1.0f + expf(-x)); }

// ---------------------------------------------------------------------------
// Generic 128x128-tile bf16 MFMA GEMM.
//  A: MxK f32 row-major (lda). Bm: BT? NxK row-major : KxN row-major (ldb).
//  EPI 0: Cout[row*ldc+col] = acc + cb[col]   (guarded col<N)
//  EPI 1: s = sum_col tanh(acc + rowbias[row/rows_per_b][col] (+cb[col])) * v[col]
//         atomicAdd(Cout[row], s)    (requires N multiple of 128)
// ---------------------------------------------------------------------------
template<bool BT, int EPI>
__device__ __forceinline__ void gemm_body(
    const float* __restrict__ A, const float* __restrict__ Bm,
    float* __restrict__ Cout, const float* __restrict__ cb,
    const float* __restrict__ rowbias, const float* __restrict__ vvec,
    int M, int N, int K, int lda, int ldb, int ldc, int rows_per_b,
    int m0, int n0)
{
    __shared__ short As[128 * 40];
    __shared__ short Bs[128 * 40];
    const int t = threadIdx.x;
    const int lane = t & 63;
    const int wv = t >> 6;
    const int l16 = lane & 15, lq = lane >> 4;
    const int wm = wv >> 1, wn = wv & 1;

    f32x4 acc[4][4];
#pragma unroll
    for (int i = 0; i < 4; ++i)
#pragma unroll
        for (int j = 0; j < 4; ++j) acc[i][j] = (f32x4){0.f, 0.f, 0.f, 0.f};

    const int ar = t >> 1;
    const int ac0 = (t & 1) << 4;

    for (int k0 = 0; k0 < K; k0 += 32) {
        {   // stage A tile (128 x 32), f32 -> bf16
            const f32x4* s4 = (const f32x4*)(A + (size_t)(m0 + ar) * lda + (k0 + ac0));
            f32x4 q0 = s4[0], q1 = s4[1], q2 = s4[2], q3 = s4[3];
            u32x4* dst = (u32x4*)(As + ar * 40 + ac0);
            dst[0] = (u32x4){pack2(q0[0],q0[1]), pack2(q0[2],q0[3]), pack2(q1[0],q1[1]), pack2(q1[2],q1[3])};
            dst[1] = (u32x4){pack2(q2[0],q2[1]), pack2(q2[2],q2[3]), pack2(q3[0],q3[1]), pack2(q3[2],q3[3])};
        }
        if (BT) {
            const f32x4* s4 = (const f32x4*)(Bm + (size_t)(n0 + ar) * ldb + (k0 + ac0));
            f32x4 q0 = s4[0], q1 = s4[1], q2 = s4[2], q3 = s4[3];
            u32x4* dst = (u32x4*)(Bs + ar * 40 + ac0);
            dst[0] = (u32x4){pack2(q0[0],q0[1]), pack2(q0[2],q0[3]), pack2(q1[0],q1[1]), pack2(q1[2],q1[3])};
            dst[1] = (u32x4){pack2(q2[0],q2[1]), pack2(q2[2],q2[3]), pack2(q3[0],q3[1]), pack2(q3[2],q3[3])};
        } else {
            // K x N layout: transpose-stage. thread -> column n, half of k.
            const int bn = t & 127, kh = t >> 7;
            const bool ok = (n0 + bn) < N;
            const float* src = Bm + (size_t)(k0 + kh * 16) * ldb + (n0 + bn);
            float f[16];
#pragma unroll
            for (int j = 0; j < 16; ++j) f[j] = ok ? src[(size_t)j * ldb] : 0.0f;
            u32x4* dst = (u32x4*)(Bs + bn * 40 + kh * 16);
            dst[0] = (u32x4){pack2(f[0],f[1]), pack2(f[2],f[3]), pack2(f[4],f[5]), pack2(f[6],f[7])};
            dst[1] = (u32x4){pack2(f[8],f[9]), pack2(f[10],f[11]), pack2(f[12],f[13]), pack2(f[14],f[15])};
        }
        __syncthreads();
        bf16x8 af[4], bfr[4];
#pragma unroll
        for (int i = 0; i < 4; ++i) af[i]  = *(const bf16x8*)(As + (wm * 64 + i * 16 + l16) * 40 + lq * 8);
#pragma unroll
        for (int i = 0; i < 4; ++i) bfr[i] = *(const bf16x8*)(Bs + (wn * 64 + i * 16 + l16) * 40 + lq * 8);
#pragma unroll
        for (int mf = 0; mf < 4; ++mf)
#pragma unroll
            for (int nf = 0; nf < 4; ++nf)
                acc[mf][nf] = __builtin_amdgcn_mfma_f32_16x16x32_bf16(af[mf], bfr[nf], acc[mf][nf], 0, 0, 0);
        __syncthreads();
    }

    if (EPI == 0) {
#pragma unroll
        for (int mf = 0; mf < 4; ++mf) {
            int gr0 = m0 + wm * 64 + mf * 16 + lq * 4;
#pragma unroll
            for (int nf = 0; nf < 4; ++nf) {
                int gc = n0 + wn * 64 + nf * 16 + l16;
                if (gc < N) {
                    float cbv = cb ? cb[gc] : 0.0f;
#pragma unroll
                    for (int r = 0; r < 4; ++r)
                        Cout[(size_t)(gr0 + r) * ldc + gc] = acc[mf][nf][r] + cbv;
                }
            }
        }
    } else {
#pragma unroll
        for (int mf = 0; mf < 4; ++mf) {
#pragma unroll
            for (int r = 0; r < 4; ++r) {
                int gr = m0 + wm * 64 + mf * 16 + lq * 4 + r;
                const float* rb = rowbias + (size_t)(gr / rows_per_b) * 1024;
                float s = 0.0f;
#pragma unroll
                for (int nf = 0; nf < 4; ++nf) {
                    int gc = n0 + wn * 64 + nf * 16 + l16;
                    float xv = acc[mf][nf][r] + rb[gc];
                    if (cb) xv += cb[gc];
                    s += tanhf(xv) * vvec[gc];
                }
#pragma unroll
                for (int msk = 1; msk < 16; msk <<= 1) s += __shfl_xor(s, msk, 64);
                if (l16 == 0) atomicAdd(&Cout[gr], s);
            }
        }
    }
}

// ------------------------------ GEMM wrappers ------------------------------
__global__ __launch_bounds__(256) void k_gemm_bn_store(
    const float* A, const float* B, float* C, const float* cb,
    int M, int N, int K, int lda, int ldb, int ldc) {
    gemm_body<false, 0>(A, B, C, cb, nullptr, nullptr, M, N, K, lda, ldb, ldc, 1,
                        (int)blockIdx.y * 128, (int)blockIdx.x * 128);
}

__global__ __launch_bounds__(256) void k_qh3(
    const float* q, const float* W0, const float* b0, const float* W1, const float* b1,
    const float* W2, const float* b2, float* o0, float* o1, float* o2) {
    const float* W = W0; const float* bb = b0; float* o = o0;
    if (blockIdx.z == 1) { W = W1; bb = b1; o = o1; }
    if (blockIdx.z == 2) { W = W2; bb = b2; o = o2; }
    gemm_body<false, 0>(q, W, o, bb, nullptr, nullptr, 128, 1024, 1024, 1024, 1024, 1024, 1,
                        0, (int)blockIdx.x * 128);
}

__global__ __launch_bounds__(256) void k_hist(
    const float* hs, const float* Wm, const float* qh, const float* v, float* sc) {
    gemm_body<false, 1>(hs, Wm, sc, nullptr, qh, v, 32768, 1024, 1024, 1024, 1024, 0, 256,
                        (int)blockIdx.y * 128, (int)blockIdx.x * 128);
}

__global__ __launch_bounds__(256) void k_att2(
    const float* se, const float* ae, const float* Ws, const float* Wa,
    const float* qs, const float* qa, const float* vs, const float* va,
    float* os, float* oa) {
    const float* A = se; const float* W = Ws; const float* qb = qs; const float* vv = vs; float* o = os;
    if (blockIdx.z == 1) { A = ae; W = Wa; qb = qa; vv = va; o = oa; }
    gemm_body<false, 1>(A, W, o, nullptr, qb, vv, 1280, 1024, 1024, 1024, 1024, 0, 10,
                        (int)blockIdx.y * 128, (int)blockIdx.x * 128);
}

__global__ __launch_bounds__(256) void k_stac2(
    const float* se, const float* ae, const float* Wmsc, const float* tagrow,
    const float* qsc, const float* vsc, float* ost, float* oac) {
    const float* A = se; const float* cb = nullptr; float* o = ost;
    if (blockIdx.z == 1) { A = ae; cb = tagrow; o = oac; }
    gemm_body<false, 1>(A, Wmsc, o, cb, qsc, vsc, 1280, 1024, 1024, 1024, 1024, 0, 10,
                        (int)blockIdx.y * 128, (int)blockIdx.x * 128);
}

__global__ __launch_bounds__(256) void k_gigh(
    const float* x, const float* h0, const float* Wih, const float* Whh,
    const float* bih, const float* bhh, float* gi, float* gh) {
    if (blockIdx.z == 0)
        gemm_body<true, 0>(x, Wih, gi, bih, nullptr, nullptr, 128, 3072, 4096, 4096, 4096, 3072, 1,
                           0, (int)blockIdx.x * 128);
    else
        gemm_body<true, 0>(h0, Whh, gh, bhh, nullptr, nullptr, 128, 3072, 1024, 1024, 1024, 3072, 1,
                           0, (int)blockIdx.x * 128);
}

// --------------------------- non-GEMM kernels ------------------------------
// masked softmax over L=256 hist scores + c_his = w @ hs_vectors -> x[:,1024:2048]
__global__ __launch_bounds__(256) void k_chis(
    const float* __restrict__ scores, const int* __restrict__ lens,
    const float* __restrict__ hs, float* __restrict__ x) {
    int b = blockIdx.x, t = threadIdx.x;
    __shared__ float w[256];
    __shared__ float red[256];
    int len = lens[b];
    float s = scores[b * 256 + t];
    bool valid = t < len;
    red[t] = valid ? s : -3.0e38f;
    __syncthreads();
    for (int st = 128; st > 0; st >>= 1) { if (t < st) red[t] = fmaxf(red[t], red[t + st]); __syncthreads(); }
    float m = red[0];
    __syncthreads();
    float e = valid ? expf(s - m) : 0.0f;
    red[t] = e;
    __syncthreads();
    for (int st = 128; st > 0; st >>= 1) { if (t < st) red[t] += red[t + st]; __syncthreads(); }
    float Z = red[0];
    __syncthreads();
    w[t] = e / Z;
    __syncthreads();
    f32x4 acc = {0.f, 0.f, 0.f, 0.f};
    for (int l = 0; l < 256; ++l) {
        float wl = w[l];
        if (wl == 0.0f) continue;
        f32x4 hv = ((const f32x4*)(hs + ((size_t)b * 256 + l) * 1024))[t];
        acc[0] += wl * hv[0]; acc[1] += wl * hv[1]; acc[2] += wl * hv[2]; acc[3] += wl * hv[3];
    }
    ((f32x4*)(x + (size_t)b * 4096 + 1024))[t] = acc;
}

__device__ __forceinline__ void softmax10(const float* src, float* dst) {
    float m = src[0];
    for (int i = 1; i < 10; ++i) m = fmaxf(m, src[i]);
    float z = 0.f, e[10];
    for (int i = 0; i < 10; ++i) { e[i] = expf(src[i] - m); z += e[i]; }
    float iz = 1.0f / z;
    for (int i = 0; i < 10; ++i) dst[i] = e[i] * iz;
}

// inp copy + state/action softmax + contexts -> x[:,0:1024], x[:,2048:4096]
__global__ __launch_bounds__(256) void k_assemble(
    const float* __restrict__ inp, const float* __restrict__ st_sc, const float* __restrict__ ac_sc,
    const float* __restrict__ se, const float* __restrict__ ae, float* __restrict__ x) {
    int b = blockIdx.x, t = threadIdx.x;
    __shared__ float sw[10], aw[10];
    if (t == 0) softmax10(st_sc + b * 10, sw);
    if (t == 1) softmax10(ac_sc + b * 10, aw);
    f32x4 iv = ((const f32x4*)(inp + (size_t)b * 1024))[t];
    ((f32x4*)(x + (size_t)b * 4096))[t] = iv;
    __syncthreads();
    f32x4 cs = {0.f,0.f,0.f,0.f}, ca = {0.f,0.f,0.f,0.f};
#pragma unroll
    for (int s = 0; s < 10; ++s) {
        f32x4 sv = ((const f32x4*)(se + ((size_t)b * 10 + s) * 1024))[t];
        f32x4 av = ((const f32x4*)(ae + ((size_t)b * 10 + s) * 1024))[t];
        float ws = sw[s], wa = aw[s];
        cs[0] += ws * sv[0]; cs[1] += ws * sv[1]; cs[2] += ws * sv[2]; cs[3] += ws * sv[3];
        ca[0] += wa * av[0]; ca[1] += wa * av[1]; ca[2] += wa * av[2]; ca[3] += wa * av[3];
    }
    ((f32x4*)(x + (size_t)b * 4096 + 2048))[t] = cs;
    ((f32x4*)(x + (size_t)b * 4096 + 3072))[t] = ca;
}

__global__ __launch_bounds__(256) void k_gru(
    const float* __restrict__ gi, const float* __restrict__ gh,
    const float* __restrict__ h0, float* __restrict__ hnew) {
    int i = blockIdx.x * 256 + threadIdx.x;   // < 131072
    int b = i >> 10, j = i & 1023;
    const float* gib = gi + (size_t)b * 3072;
    const float* ghb = gh + (size_t)b * 3072;
    float r = sigm(gib[j] + ghb[j]);
    float z = sigm(gib[1024 + j] + ghb[1024 + j]);
    float n = tanhf(gib[2048 + j] + r * ghb[2048 + j]);
    float h0v = h0[i];
    hnew[i] = (1.0f - z) * n + z * h0v;
}

// hs_logits[b,l] = h_new[b] . hs_vectors[b,l]  (fp32 exact)
__global__ __launch_bounds__(256) void k_hsl(
    const float* __restrict__ hnew, const float* __restrict__ hs, float* __restrict__ out) {
    int b = blockIdx.y;
    int w = threadIdx.x >> 6, lane = threadIdx.x & 63;
    int l = blockIdx.x * 4 + w;
    const f32x4* hr = (const f32x4*)(hnew + (size_t)b * 1024);
    const f32x4* vr = (const f32x4*)(hs + ((size_t)b * 256 + l) * 1024);
    float s = 0.f;
#pragma unroll
    for (int q = 0; q < 4; ++q) {
        f32x4 a = hr[lane * 4 + q], c = vr[lane * 4 + q];
        s += a[0]*c[0] + a[1]*c[1] + a[2]*c[2] + a[3]*c[3];
    }
    for (int msk = 1; msk < 64; msk <<= 1) s += __shfl_xor(s, msk, 64);
    if (lane == 0) out[b * 256 + l] = s;
}

// max & sumexp over concat[gene(40000) | hs(256) | st(10) | ac(10)]
__global__ __launch_bounds__(256) void k_smstats(
    const float* __restrict__ gene, const float* __restrict__ hsl,
    const float* __restrict__ stl, const float* __restrict__ acl,
    float* __restrict__ mbuf, float* __restrict__ zbuf) {
    int b = blockIdx.x, t = threadIdx.x;
    __shared__ float red[256];
    const f32x4* g4 = (const f32x4*)(gene + (size_t)b * 40000);
    float mx = -3.0e38f;
    for (int i = t; i < 10000; i += 256) {
        f32x4 q = g4[i];
        mx = fmaxf(mx, fmaxf(fmaxf(q[0], q[1]), fmaxf(q[2], q[3])));
    }
    mx = fmaxf(mx, hsl[b * 256 + t]);
    if (t < 10) mx = fmaxf(mx, fmaxf(stl[b * 10 + t], acl[b * 10 + t]));
    red[t] = mx; __syncthreads();
    for (int s = 128; s > 0; s >>= 1) { if (t < s) red[t] = fmaxf(red[t], red[t + s]); __syncthreads(); }
    float m = red[0];
    __syncthreads();
    float sum = 0.f;
    for (int i = t; i < 10000; i += 256) {
        f32x4 q = g4[i];
        sum += expf(q[0] - m) + expf(q[1] - m) + expf(q[2] - m) + expf(q[3] - m);
    }
    sum += expf(hsl[b * 256 + t] - m);
    if (t < 10) sum += expf(stl[b * 10 + t] - m) + expf(acl[b * 10 + t] - m);
    red[t] = sum; __syncthreads();
    for (int s = 128; s > 0; s >>= 1) { if (t < s) red[t] += red[t + s]; __syncthreads(); }
    if (t == 0) { mbuf[b] = m; zbuf[b] = red[0]; }
}

__global__ __launch_bounds__(256) void k_scatter(
    const float* __restrict__ hsl, const float* __restrict__ mbuf, const float* __restrict__ zbuf,
    const int* __restrict__ hwi, float* __restrict__ copyp) {
    int b = blockIdx.x, l = threadIdx.x;
    float wv = expf(hsl[b * 256 + l] - mbuf[b]) / zbuf[b];
    int idx = hwi[b * 256 + l];
    atomicAdd(copyp + (size_t)b * 40000 + idx, wv);
}

// out = log( softmax_gene + sum_s sw*sprob + sum_a aw*aprob + copy_p ), in place over gene logits
__global__ __launch_bounds__(256) void k_final(
    float* __restrict__ gene_out, const float* __restrict__ copyp,
    const float* __restrict__ sprob, const float* __restrict__ aprob,
    const float* __restrict__ stl, const float* __restrict__ acl,
    const float* __restrict__ mbuf, const float* __restrict__ zbuf) {
    int b = blockIdx.y, t = threadIdx.x;
    __shared__ float sw[10], aw[10];
    float m = mbuf[b], iz = 1.0f / zbuf[b];
    if (t < 10) sw[t] = expf(stl[b * 10 + t] - m) * iz;
    if (t >= 64 && t < 74) aw[t - 64] = expf(acl[b * 10 + (t - 64)] - m) * iz;
    __syncthreads();
    int v4 = blockIdx.x * 256 + t;
    if (v4 < 10000) {
        size_t base = (size_t)b * 10000 + v4;
        f32x4 g = ((const f32x4*)gene_out)[base];
        f32x4 c = ((const f32x4*)copyp)[base];
        f32x4 acc;
#pragma unroll
        for (int j = 0; j < 4; ++j) acc[j] = expf(g[j] - m) * iz + c[j];
#pragma unroll
        for (int s = 0; s < 10; ++s) {
            f32x4 pv = ((const f32x4*)sprob)[((size_t)b * 10 + s) * 10000 + v4];
            f32x4 av = ((const f32x4*)aprob)[((size_t)b * 10 + s) * 10000 + v4];
            float ws = sw[s], wa = aw[s];
#pragma unroll
            for (int j = 0; j < 4; ++j) acc[j] += ws * pv[j] + wa * av[j];
        }
        f32x4 r;
#pragma unroll
        for (int j = 0; j < 4; ++j) r[j] = logf(acc[j]);
        ((f32x4*)gene_out)[base] = r;
    }
}

// ------------------------------- launcher ----------------------------------
// ws layout (floats)
#define OFF_QH_H  0
#define OFF_QH_S  131072
#define OFF_QH_A  262144
#define OFF_QSC   393216
#define OFF_X     524288
#define OFF_GI    1048576
#define OFF_GH    1441792
#define OFF_HSC   1835008
#define OFF_STSC  1867776
#define OFF_ACSC  1869056
#define OFF_STLG  1870336
#define OFF_ACLG  1871616
#define OFF_HSL   1872896
#define OFF_M     1905664
#define OFF_Z     1905792
#define OFF_COPY  1905920

extern "C" void kernel_launch(void* const* d_in, const int* in_sizes, int n_in,
                              void* d_out, int out_size, void* d_ws, size_t ws_size,
                              hipStream_t stream) {
    const float* inp     = (const float*)d_in[0];
    const float* hidden  = (const float*)d_in[1];
    const float* hs      = (const float*)d_in[2];
    const float* sprob   = (const float*)d_in[3];
    const float* se      = (const float*)d_in[4];
    const float* aprob   = (const float*)d_in[5];
    const float* ae      = (const float*)d_in[6];
    const int*   lens    = (const int*)d_in[7];
    const int*   hwi     = (const int*)d_in[8];
    const float* Wq_hist = (const float*)d_in[9];
    const float* bq_hist = (const float*)d_in[10];
    const float* Wm_hist = (const float*)d_in[11];
    const float* v_hist  = (const float*)d_in[12];
    const float* Wq_s    = (const float*)d_in[13];
    const float* bq_s    = (const float*)d_in[14];
    const float* Wm_s    = (const float*)d_in[15];
    const float* v_s     = (const float*)d_in[16];
    const float* Wq_a    = (const float*)d_in[17];
    const float* bq_a    = (const float*)d_in[18];
    const float* Wm_a    = (const float*)d_in[19];
    const float* v_a     = (const float*)d_in[20];
    const float* Wq_sc   = (const float*)d_in[21];
    const float* bq_sc   = (const float*)d_in[22];
    const float* Wm_sc   = (const float*)d_in[23];
    const float* v_sc    = (const float*)d_in[24];
    const float* W_ih    = (const float*)d_in[25];
    const float* W_hh    = (const float*)d_in[26];
    const float* b_ih    = (const float*)d_in[27];
    const float* b_hh    = (const float*)d_in[28];
    const float* W_out   = (const float*)d_in[29];
    const float* b_out   = (const float*)d_in[30];

    float* out  = (float*)d_out;
    float* w    = (float*)d_ws;
    float* hnew = out + BV;

    float* qh_h  = w + OFF_QH_H;
    float* qh_s  = w + OFF_QH_S;
    float* qh_a  = w + OFF_QH_A;
    float* qsc   = w + OFF_QSC;
    float* xbuf  = w + OFF_X;
    float* gi    = w + OFF_GI;
    float* gh    = w + OFF_GH;
    float* hsc   = w + OFF_HSC;
    float* stsc  = w + OFF_STSC;
    float* acsc  = w + OFF_ACSC;
    float* stlg  = w + OFF_STLG;
    float* aclg  = w + OFF_ACLG;
    float* hsl   = w + OFF_HSL;
    float* mbuf  = w + OFF_M;
    float* zbuf  = w + OFF_Z;
    float* copyp = w + OFF_COPY;

    dim3 blk(256);

    // zero atomic-accumulated score buffers (hsc..aclg contiguous) and copy_p
    hipMemsetAsync(hsc, 0, (size_t)(32768 + 4 * 1280) * 4, stream);
    hipMemsetAsync(copyp, 0, (size_t)BV * 4, stream);

    // q0 @ {Wq_hist, Wq_s, Wq_a} + biases
    k_qh3<<<dim3(8, 1, 3), blk, 0, stream>>>(hidden, Wq_hist, bq_hist, Wq_s, bq_s, Wq_a, bq_a,
                                             qh_h, qh_s, qh_a);
    // hist MLP scores (the big GEMM)
    k_hist<<<dim3(8, 256), blk, 0, stream>>>(hs, Wm_hist, qh_h, v_hist, hsc);
    // state/action attention MLP scores
    k_att2<<<dim3(8, 10, 2), blk, 0, stream>>>(se, ae, Wm_s, Wm_a, qh_s, qh_a, v_s, v_a, stsc, acsc);
    // contexts -> x
    k_chis<<<dim3(128), blk, 0, stream>>>(hsc, lens, hs, xbuf);
    k_assemble<<<dim3(128), blk, 0, stream>>>(inp, stsc, acsc, se, ae, xbuf);
    // GRU gates
    k_gigh<<<dim3(24, 1, 2), blk, 0, stream>>>(xbuf, hidden, W_ih, W_hh, b_ih, b_hh, gi, gh);
    k_gru<<<dim3(512), blk, 0, stream>>>(gi, gh, hidden, hnew);
    // copy-scorer query and gene logits
    k_gemm_bn_store<<<dim3(8, 1), blk, 0, stream>>>(hnew, Wq_sc, qsc, bq_sc, 128, 1024, 1024, 1024, 1024, 1024);
    k_gemm_bn_store<<<dim3(313, 1), blk, 0, stream>>>(hnew, W_out, out, b_out, 128, 40000, 1024, 1024, 40000, 40000);
    // hs / st / ac logits
    k_hsl<<<dim3(64, 128), blk, 0, stream>>>(hnew, hs, hsl);
    k_stac2<<<dim3(8, 10, 2), blk, 0, stream>>>(se, ae, Wm_sc, Wm_sc + (size_t)1024 * 1024, qsc, v_sc, stlg, aclg);
    // softmax over 40276, scatter, final fused output
    k_smstats<<<dim3(128), blk, 0, stream>>>(out, hsl, stlg, aclg, mbuf, zbuf);
    k_scatter<<<dim3(128), blk, 0, stream>>>(hsl, mbuf, zbuf, hwi, copyp);
    k_final<<<dim3(40, 128), blk, 0, stream>>>(out, copyp, sprob, aprob, stlg, aclg, mbuf, zbuf);

    (void)in_sizes; (void)n_in; (void)out_size; (void)ws_size;
}

// Round 2
// 652.690 us; speedup vs baseline: 1.6209x; 1.6209x over previous
//
#include <hip/hip_runtime.h>
#include <stdint.h>

typedef __attribute__((ext_vector_type(4))) float f32x4;
typedef __attribute__((ext_vector_type(2))) unsigned int u32x2;
typedef __attribute__((ext_vector_type(4))) unsigned int u32x4;
typedef __attribute__((ext_vector_type(8))) short bf16x8;

#define BV (128*40000)

__device__ __forceinline__ unsigned rne_bf16(float f) {
    unsigned x = __float_as_uint(f);
    return ((x + 0x7FFFu + ((x >> 16) & 1u)) >> 16) & 0xFFFFu;
}
__device__ __forceinline__ unsigned pack2(float a, float b) {
    return rne_bf16(a) | (rne_bf16(b) << 16);
}
__device__ __forceinline__ float bf2f(unsigned u) {
    return __uint_as_float((u & 0xFFFFu) << 16);
}
__device__ __forceinline__ float sigm(float x) { return 1.0f / (1.0f + expf(-x)); }

__device__ __forceinline__ void gload16(const void* g, void* l) {
    __builtin_amdgcn_global_load_lds(
        (const __attribute__((address_space(1))) unsigned*)g,
        (__attribute__((address_space(3))) unsigned*)l, 16, 0, 0);
}

// ---------------------------------------------------------------------------
// m97-style bf16 MFMA GEMM: 128x128 tile, BK=32, double-buffered LDS,
// global_load_lds staging (both operands bf16, Bt is N x K row-major).
// EPI 1: tanh-reduce:  atomicAdd(out[row], sum_col tanh(acc+rb[row/rpb][col]
//        +cb1[col](+cb2[col]))*v[col])
// EPI 2: atomicAdd(out[row*ldc+col], acc)   (split-K accumulate)
// ---------------------------------------------------------------------------
template<int EPI>
__device__ __forceinline__ void mgemm(
    const unsigned short* __restrict__ A, const unsigned short* __restrict__ Bt,
    float* __restrict__ out, const float* __restrict__ rb,
    const float* __restrict__ cb1, const float* __restrict__ cb2,
    const float* __restrict__ vvec,
    int m0, int n0, int kb, int ke, int ldk, int ldc, int rpb)
{
    __shared__ unsigned short As[2][4096];
    __shared__ unsigned short Bs[2][4096];
    const int t = threadIdx.x, lane = t & 63, wv = t >> 6;
    const int l16 = lane & 15, lq = lane >> 4;
    const int wm = wv >> 1, wn = wv & 1;

    const int srow = lane >> 2, scol = (lane & 3) << 3;
    const unsigned short* gA0 = A + (size_t)(m0 + (wv << 4) + srow) * ldk + kb + scol;
    const unsigned short* gA1 = gA0 + (size_t)64 * ldk;
    const unsigned short* gB0 = Bt + (size_t)(n0 + (wv << 4) + srow) * ldk + kb + scol;
    const unsigned short* gB1 = gB0 + (size_t)64 * ldk;
    unsigned short* lA0 = &As[0][wv << 9];
    unsigned short* lA1 = &As[0][(wv + 4) << 9];
    unsigned short* lB0 = &Bs[0][wv << 9];
    unsigned short* lB1 = &Bs[0][(wv + 4) << 9];

    f32x4 acc[4][4];
#pragma unroll
    for (int i = 0; i < 4; ++i)
#pragma unroll
        for (int j = 0; j < 4; ++j) acc[i][j] = (f32x4){0.f, 0.f, 0.f, 0.f};

    const int NS = (ke - kb) >> 5;
    gload16(gA0, lA0); gload16(gA1, lA1);
    gload16(gB0, lB0); gload16(gB1, lB1);

    for (int s = 0; s < NS; ++s) {
        __syncthreads();
        if (s + 1 < NS) {
            const int nb = (s + 1) & 1, ko = (s + 1) << 5;
            gload16(gA0 + ko, lA0 + (nb << 12)); gload16(gA1 + ko, lA1 + (nb << 12));
            gload16(gB0 + ko, lB0 + (nb << 12)); gload16(gB1 + ko, lB1 + (nb << 12));
        }
        const unsigned short* ab = As[s & 1];
        const unsigned short* bb = Bs[s & 1];
        bf16x8 af[4], bfv[4];
#pragma unroll
        for (int i = 0; i < 4; ++i)
            af[i] = *(const bf16x8*)(ab + (((wm << 6) + (i << 4) + l16) << 5) + (lq << 3));
#pragma unroll
        for (int i = 0; i < 4; ++i)
            bfv[i] = *(const bf16x8*)(bb + (((wn << 6) + (i << 4) + l16) << 5) + (lq << 3));
#pragma unroll
        for (int mf = 0; mf < 4; ++mf)
#pragma unroll
            for (int nf = 0; nf < 4; ++nf)
                acc[mf][nf] = __builtin_amdgcn_mfma_f32_16x16x32_bf16(af[mf], bfv[nf], acc[mf][nf], 0, 0, 0);
    }

    if (EPI == 1) {
#pragma unroll
        for (int mf = 0; mf < 4; ++mf) {
#pragma unroll
            for (int r = 0; r < 4; ++r) {
                int gr = m0 + (wm << 6) + (mf << 4) + (lq << 2) + r;
                const float* rbp = rb + (size_t)(gr / rpb) * 1024;
                float s = 0.0f;
#pragma unroll
                for (int nf = 0; nf < 4; ++nf) {
                    int gc = n0 + (wn << 6) + (nf << 4) + l16;
                    float xv = acc[mf][nf][r] + rbp[gc] + cb1[gc];
                    if (cb2) xv += cb2[gc];
                    s += tanhf(xv) * vvec[gc];
                }
#pragma unroll
                for (int msk = 1; msk < 16; msk <<= 1) s += __shfl_xor(s, msk, 64);
                if (l16 == 0) atomicAdd(&out[gr], s);
            }
        }
    } else {
#pragma unroll
        for (int mf = 0; mf < 4; ++mf) {
            int gr0 = m0 + (wm << 6) + (mf << 4) + (lq << 2);
#pragma unroll
            for (int nf = 0; nf < 4; ++nf) {
                int gc = n0 + (wn << 6) + (nf << 4) + l16;
#pragma unroll
                for (int r = 0; r < 4; ++r)
                    atomicAdd(&out[(size_t)(gr0 + r) * ldc + gc], acc[mf][nf][r]);
            }
        }
    }
}

// ------------------------------ GEMM wrappers ------------------------------
__global__ __launch_bounds__(256) void k_hist2(
    const unsigned short* hs, const unsigned short* WmhT, const int* lens,
    const float* qh_h, const float* bq, const float* v, float* hsc) {
    int h = blockIdx.x;
    int p = h & 255, n = h >> 8;            // XCD swizzle: siblings (same p) share XCD p%8
    int b = p >> 1, l0 = (p & 1) << 7;
    if (lens[b] <= l0) return;               // fully-masked row block
    mgemm<1>(hs, WmhT, hsc, qh_h, bq, nullptr, v, p << 7, n << 7, 0, 1024, 1024, 0, 256);
}

__global__ __launch_bounds__(256) void k_att3(
    const unsigned short* se, const unsigned short* ae,
    const unsigned short* WmsT, const unsigned short* WmaT,
    const float* qh_s, const float* qh_a, const float* bq_s, const float* bq_a,
    const float* v_s, const float* v_a, float* stsc, float* acsc) {
    if (blockIdx.z == 0)
        mgemm<1>(se, WmsT, stsc, qh_s, bq_s, nullptr, v_s, blockIdx.y * 128, blockIdx.x * 128, 0, 1024, 1024, 0, 10);
    else
        mgemm<1>(ae, WmaT, acsc, qh_a, bq_a, nullptr, v_a, blockIdx.y * 128, blockIdx.x * 128, 0, 1024, 1024, 0, 10);
}

__global__ __launch_bounds__(256) void k_stac3(
    const unsigned short* se, const unsigned short* ae, const unsigned short* WmscT,
    const float* tagrow, const float* qsc, const float* bq_sc, const float* v_sc,
    float* stlg, float* aclg) {
    if (blockIdx.z == 0)
        mgemm<1>(se, WmscT, stlg, qsc, bq_sc, nullptr, v_sc, blockIdx.y * 128, blockIdx.x * 128, 0, 1024, 1024, 0, 10);
    else
        mgemm<1>(ae, WmscT, aclg, qsc, bq_sc, tagrow, v_sc, blockIdx.y * 128, blockIdx.x * 128, 0, 1024, 1024, 0, 10);
}

__global__ __launch_bounds__(256) void k_qh4(
    const unsigned short* q0, const unsigned short* W0, const unsigned short* W1,
    const unsigned short* W2, float* o0, float* o1, float* o2) {
    const unsigned short* W = W0; float* o = o0;
    if (blockIdx.z == 1) { W = W1; o = o1; }
    if (blockIdx.z == 2) { W = W2; o = o2; }
    int kb = blockIdx.y << 8;
    mgemm<2>(q0, W, o, nullptr, nullptr, nullptr, nullptr, 0, blockIdx.x * 128, kb, kb + 256, 1024, 1024, 1);
}

__global__ __launch_bounds__(256) void k_gigh2(
    const unsigned short* xb, const unsigned short* q0,
    const unsigned short* Wih, const unsigned short* Whh, float* gi, float* gh) {
    if (blockIdx.z == 0) {
        int kb = blockIdx.y << 9;
        mgemm<2>(xb, Wih, gi, nullptr, nullptr, nullptr, nullptr, 0, blockIdx.x * 128, kb, kb + 512, 4096, 3072, 1);
    } else {
        if (blockIdx.y >= 2) return;
        int kb = blockIdx.y << 9;
        mgemm<2>(q0, Whh, gh, nullptr, nullptr, nullptr, nullptr, 0, blockIdx.x * 128, kb, kb + 512, 1024, 3072, 1);
    }
}

__global__ __launch_bounds__(256) void k_qsc2(
    const unsigned short* hnb, const unsigned short* WqscT, float* qsc) {
    int kb = blockIdx.y << 9;
    mgemm<2>(hnb, WqscT, qsc, nullptr, nullptr, nullptr, nullptr, 0, blockIdx.x * 128, kb, kb + 512, 1024, 1024, 1);
}

// gene logits: A = hnew bf16 (gload_lds), B = W_out f32 KxN (reg-stage cvt), split-K 2
__global__ __launch_bounds__(256) void k_geneKN(
    const unsigned short* __restrict__ hnb, const float* __restrict__ Wout,
    float* __restrict__ out) {
    __shared__ unsigned short As[2][4096];
    __shared__ unsigned short Bs[2][4096];
    const int t = threadIdx.x, lane = t & 63, wv = t >> 6;
    const int l16 = lane & 15, lq = lane >> 4;
    const int wm = wv >> 1, wn = wv & 1;
    const int n0 = blockIdx.x << 7;
    const int kb = blockIdx.y << 9;

    const int srow = lane >> 2, scol = (lane & 3) << 3;
    const unsigned short* gA0 = hnb + (size_t)((wv << 4) + srow) * 1024 + kb + scol;
    const unsigned short* gA1 = gA0 + (size_t)64 * 1024;
    unsigned short* lA0 = &As[0][wv << 9];
    unsigned short* lA1 = &As[0][(wv + 4) << 9];

    const int bn = t & 127, kh = t >> 7;
    const bool ok = (n0 + bn) < 40000;
    const float* gB = Wout + (size_t)(kb + kh * 16) * 40000 + (n0 + bn);

    f32x4 acc[4][4];
#pragma unroll
    for (int i = 0; i < 4; ++i)
#pragma unroll
        for (int j = 0; j < 4; ++j) acc[i][j] = (f32x4){0.f, 0.f, 0.f, 0.f};

    auto stageB = [&](int buf, int ko) {
        const float* src = gB + (size_t)ko * 40000;
        float f[16];
#pragma unroll
        for (int j = 0; j < 16; ++j) f[j] = ok ? src[(size_t)j * 40000] : 0.0f;
        u32x4* d = (u32x4*)&Bs[buf][bn * 32 + kh * 16];
        d[0] = (u32x4){pack2(f[0],f[1]), pack2(f[2],f[3]), pack2(f[4],f[5]), pack2(f[6],f[7])};
        d[1] = (u32x4){pack2(f[8],f[9]), pack2(f[10],f[11]), pack2(f[12],f[13]), pack2(f[14],f[15])};
    };

    gload16(gA0, lA0); gload16(gA1, lA1); stageB(0, 0);
    for (int s = 0; s < 16; ++s) {
        __syncthreads();
        if (s + 1 < 16) {
            const int nb = (s + 1) & 1, ko = (s + 1) << 5;
            gload16(gA0 + ko, lA0 + (nb << 12)); gload16(gA1 + ko, lA1 + (nb << 12));
            stageB(nb, ko);
        }
        const unsigned short* ab = As[s & 1];
        const unsigned short* bb = Bs[s & 1];
        bf16x8 af[4], bfv[4];
#pragma unroll
        for (int i = 0; i < 4; ++i)
            af[i] = *(const bf16x8*)(ab + (((wm << 6) + (i << 4) + l16) << 5) + (lq << 3));
#pragma unroll
        for (int i = 0; i < 4; ++i)
            bfv[i] = *(const bf16x8*)(bb + (((wn << 6) + (i << 4) + l16) << 5) + (lq << 3));
#pragma unroll
        for (int mf = 0; mf < 4; ++mf)
#pragma unroll
            for (int nf = 0; nf < 4; ++nf)
                acc[mf][nf] = __builtin_amdgcn_mfma_f32_16x16x32_bf16(af[mf], bfv[nf], acc[mf][nf], 0, 0, 0);
    }
#pragma unroll
    for (int mf = 0; mf < 4; ++mf) {
        int gr0 = (wm << 6) + (mf << 4) + (lq << 2);
#pragma unroll
        for (int nf = 0; nf < 4; ++nf) {
            int gc = n0 + (wn << 6) + (nf << 4) + l16;
            if (gc < 40000) {
#pragma unroll
                for (int r = 0; r < 4; ++r)
                    atomicAdd(&out[(size_t)(gr0 + r) * 40000 + gc], acc[mf][nf][r]);
            }
        }
    }
}

// --------------------------- prep kernels -----------------------------------
__global__ __launch_bounds__(256) void k_cvt(const float* __restrict__ in,
                                             unsigned short* __restrict__ o, int n8) {
    int i = blockIdx.x * 256 + threadIdx.x;
    if (i >= n8) return;
    const f32x4* s = (const f32x4*)in + (size_t)i * 2;
    f32x4 a = s[0], b = s[1];
    ((u32x4*)o)[i] = (u32x4){pack2(a[0],a[1]), pack2(a[2],a[3]), pack2(b[0],b[1]), pack2(b[2],b[3])};
}

struct TrArgs { const float* s[8]; unsigned short* d[8]; };
__global__ __launch_bounds__(256) void k_trcvt(TrArgs a) {
    __shared__ float tile[64][65];
    const float* in = a.s[blockIdx.z];
    unsigned short* ot = a.d[blockIdx.z];
    int k0 = blockIdx.y << 6, n0 = blockIdx.x << 6;
    int tr = threadIdx.x >> 6, tc = threadIdx.x & 63;
#pragma unroll
    for (int i = 0; i < 16; ++i) {
        int r = (i << 2) + tr;
        tile[r][tc] = in[(size_t)(k0 + r) * 1024 + n0 + tc];
    }
    __syncthreads();
#pragma unroll
    for (int i = 0; i < 16; ++i) {
        int r = (i << 2) + tr;
        ot[(size_t)(n0 + r) * 1024 + k0 + tc] = (unsigned short)rne_bf16(tile[tc][r]);
    }
}

// --------------------------- non-GEMM kernels ------------------------------
__device__ __forceinline__ void softmax10(const float* src, float* dst) {
    float m = src[0];
    for (int i = 1; i < 10; ++i) m = fmaxf(m, src[i]);
    float z = 0.f, e[10];
    for (int i = 0; i < 10; ++i) { e[i] = expf(src[i] - m); z += e[i]; }
    float iz = 1.0f / z;
    for (int i = 0; i < 10; ++i) dst[i] = e[i] * iz;
}

__global__ __launch_bounds__(256) void k_chis(
    const float* __restrict__ scores, const int* __restrict__ lens,
    const unsigned short* __restrict__ hs, unsigned short* __restrict__ xb) {
    int b = blockIdx.x, t = threadIdx.x;
    __shared__ float w[256];
    __shared__ float red[256];
    int len = lens[b];
    float s = scores[b * 256 + t];
    bool valid = t < len;
    red[t] = valid ? s : -3.0e38f;
    __syncthreads();
    for (int st = 128; st > 0; st >>= 1) { if (t < st) red[t] = fmaxf(red[t], red[t + st]); __syncthreads(); }
    float m = red[0];
    __syncthreads();
    float e = valid ? expf(s - m) : 0.0f;
    red[t] = e;
    __syncthreads();
    for (int st = 128; st > 0; st >>= 1) { if (t < st) red[t] += red[t + st]; __syncthreads(); }
    float Z = red[0];
    __syncthreads();
    w[t] = e / Z;
    __syncthreads();
    float a0 = 0.f, a1 = 0.f, a2 = 0.f, a3 = 0.f;
    for (int l = 0; l < 256; ++l) {
        float wl = w[l];
        if (wl == 0.0f) continue;
        u32x2 u = *((const u32x2*)(hs + ((size_t)b * 256 + l) * 1024) + t);
        a0 += wl * bf2f(u[0]); a1 += wl * bf2f(u[0] >> 16);
        a2 += wl * bf2f(u[1]); a3 += wl * bf2f(u[1] >> 16);
    }
    *((u32x2*)(xb + (size_t)b * 4096 + 1024) + t) = (u32x2){pack2(a0, a1), pack2(a2, a3)};
}

__global__ __launch_bounds__(256) void k_assemble(
    const float* __restrict__ inp, const float* __restrict__ st_sc, const float* __restrict__ ac_sc,
    const unsigned short* __restrict__ se, const unsigned short* __restrict__ ae,
    unsigned short* __restrict__ xb) {
    int b = blockIdx.x, t = threadIdx.x;
    __shared__ float sw[10], aw[10];
    if (t == 0) softmax10(st_sc + b * 10, sw);
    if (t == 64) softmax10(ac_sc + b * 10, aw);
    f32x4 iv = ((const f32x4*)(inp + (size_t)b * 1024))[t];
    *((u32x2*)(xb + (size_t)b * 4096) + t) = (u32x2){pack2(iv[0], iv[1]), pack2(iv[2], iv[3])};
    __syncthreads();
    float cs0=0,cs1=0,cs2=0,cs3=0, ca0=0,ca1=0,ca2=0,ca3=0;
#pragma unroll
    for (int s = 0; s < 10; ++s) {
        u32x2 us = *((const u32x2*)(se + ((size_t)b * 10 + s) * 1024) + t);
        u32x2 ua = *((const u32x2*)(ae + ((size_t)b * 10 + s) * 1024) + t);
        float ws = sw[s], wa = aw[s];
        cs0 += ws * bf2f(us[0]); cs1 += ws * bf2f(us[0] >> 16);
        cs2 += ws * bf2f(us[1]); cs3 += ws * bf2f(us[1] >> 16);
        ca0 += wa * bf2f(ua[0]); ca1 += wa * bf2f(ua[0] >> 16);
        ca2 += wa * bf2f(ua[1]); ca3 += wa * bf2f(ua[1] >> 16);
    }
    *((u32x2*)(xb + (size_t)b * 4096 + 2048) + t) = (u32x2){pack2(cs0, cs1), pack2(cs2, cs3)};
    *((u32x2*)(xb + (size_t)b * 4096 + 3072) + t) = (u32x2){pack2(ca0, ca1), pack2(ca2, ca3)};
}

__global__ __launch_bounds__(256) void k_gru(
    const float* __restrict__ gi, const float* __restrict__ gh,
    const float* __restrict__ b_ih, const float* __restrict__ b_hh,
    const float* __restrict__ h0, float* __restrict__ hnew,
    unsigned short* __restrict__ hnb) {
    int i = blockIdx.x * 256 + threadIdx.x;
    int b = i >> 10, j = i & 1023;
    const float* gib = gi + (size_t)b * 3072;
    const float* ghb = gh + (size_t)b * 3072;
    float ir = gib[j] + b_ih[j],           hr = ghb[j] + b_hh[j];
    float iz = gib[1024 + j] + b_ih[1024 + j], hz = ghb[1024 + j] + b_hh[1024 + j];
    float in = gib[2048 + j] + b_ih[2048 + j], hn = ghb[2048 + j] + b_hh[2048 + j];
    float r = sigm(ir + hr);
    float z = sigm(iz + hz);
    float n = tanhf(in + r * hn);
    float h = (1.0f - z) * n + z * h0[i];
    hnew[i] = h;
    hnb[i] = (unsigned short)rne_bf16(h);
}

__global__ __launch_bounds__(256) void k_hsl(
    const float* __restrict__ hnew, const unsigned short* __restrict__ hs,
    float* __restrict__ out) {
    int b = blockIdx.y;
    int w = threadIdx.x >> 6, lane = threadIdx.x & 63;
    int l = blockIdx.x * 4 + w;
    const f32x4* hr = (const f32x4*)(hnew + (size_t)b * 1024);
    const u32x4* vr = (const u32x4*)(hs + ((size_t)b * 256 + l) * 1024);
    float s = 0.f;
#pragma unroll
    for (int q = 0; q < 2; ++q) {
        u32x4 u = vr[lane * 2 + q];
        f32x4 h0 = hr[lane * 4 + q * 2], h1 = hr[lane * 4 + q * 2 + 1];
        s += h0[0]*bf2f(u[0]) + h0[1]*bf2f(u[0]>>16) + h0[2]*bf2f(u[1]) + h0[3]*bf2f(u[1]>>16);
        s += h1[0]*bf2f(u[2]) + h1[1]*bf2f(u[2]>>16) + h1[2]*bf2f(u[3]) + h1[3]*bf2f(u[3]>>16);
    }
    for (int msk = 1; msk < 64; msk <<= 1) s += __shfl_xor(s, msk, 64);
    if (lane == 0) out[b * 256 + l] = s;
}

__global__ __launch_bounds__(256) void k_smstats(
    const float* __restrict__ gene, const float* __restrict__ bo,
    const float* __restrict__ hsl, const float* __restrict__ stl, const float* __restrict__ acl,
    float* __restrict__ mbuf, float* __restrict__ zbuf) {
    int b = blockIdx.x, t = threadIdx.x;
    __shared__ float red[256];
    const f32x4* g4 = (const f32x4*)(gene + (size_t)b * 40000);
    const f32x4* b4 = (const f32x4*)bo;
    float mx = -3.0e38f;
    for (int i = t; i < 10000; i += 256) {
        f32x4 q = g4[i], bb = b4[i];
        mx = fmaxf(mx, fmaxf(fmaxf(q[0]+bb[0], q[1]+bb[1]), fmaxf(q[2]+bb[2], q[3]+bb[3])));
    }
    mx = fmaxf(mx, hsl[b * 256 + t]);
    if (t < 10) mx = fmaxf(mx, fmaxf(stl[b * 10 + t], acl[b * 10 + t]));
    red[t] = mx; __syncthreads();
    for (int s = 128; s > 0; s >>= 1) { if (t < s) red[t] = fmaxf(red[t], red[t + s]); __syncthreads(); }
    float m = red[0];
    __syncthreads();
    float sum = 0.f;
    for (int i = t; i < 10000; i += 256) {
        f32x4 q = g4[i], bb = b4[i];
        sum += expf(q[0]+bb[0]-m) + expf(q[1]+bb[1]-m) + expf(q[2]+bb[2]-m) + expf(q[3]+bb[3]-m);
    }
    sum += expf(hsl[b * 256 + t] - m);
    if (t < 10) sum += expf(stl[b * 10 + t] - m) + expf(acl[b * 10 + t] - m);
    red[t] = sum; __syncthreads();
    for (int s = 128; s > 0; s >>= 1) { if (t < s) red[t] += red[t + s]; __syncthreads(); }
    if (t == 0) { mbuf[b] = m; zbuf[b] = red[0]; }
}

__global__ __launch_bounds__(256) void k_scatter(
    const float* __restrict__ hsl, const float* __restrict__ mbuf, const float* __restrict__ zbuf,
    const int* __restrict__ hwi, float* __restrict__ copyp) {
    int b = blockIdx.x, l = threadIdx.x;
    float wv = expf(hsl[b * 256 + l] - mbuf[b]) / zbuf[b];
    int idx = hwi[b * 256 + l];
    atomicAdd(copyp + (size_t)b * 40000 + idx, wv);
}

__global__ __launch_bounds__(256) void k_final(
    float* __restrict__ gene_out, const float* __restrict__ bo, const float* __restrict__ copyp,
    const float* __restrict__ sprob, const float* __restrict__ aprob,
    const float* __restrict__ stl, const float* __restrict__ acl,
    const float* __restrict__ mbuf, const float* __restrict__ zbuf) {
    int b = blockIdx.y, t = threadIdx.x;
    __shared__ float sw[10], aw[10];
    float m = mbuf[b], iz = 1.0f / zbuf[b];
    if (t < 10) sw[t] = expf(stl[b * 10 + t] - m) * iz;
    if (t >= 64 && t < 74) aw[t - 64] = expf(acl[b * 10 + (t - 64)] - m) * iz;
    __syncthreads();
    int v4 = blockIdx.x * 256 + t;
    if (v4 < 10000) {
        size_t base = (size_t)b * 10000 + v4;
        f32x4 g = ((const f32x4*)gene_out)[base];
        f32x4 bb = ((const f32x4*)bo)[v4];
        f32x4 c = ((const f32x4*)copyp)[base];
        f32x4 acc;
#pragma unroll
        for (int j = 0; j < 4; ++j) acc[j] = expf(g[j] + bb[j] - m) * iz + c[j];
#pragma unroll
        for (int s = 0; s < 10; ++s) {
            f32x4 pv = ((const f32x4*)sprob)[((size_t)b * 10 + s) * 10000 + v4];
            f32x4 av = ((const f32x4*)aprob)[((size_t)b * 10 + s) * 10000 + v4];
            float ws = sw[s], wa = aw[s];
#pragma unroll
            for (int j = 0; j < 4; ++j) acc[j] += ws * pv[j] + wa * av[j];
        }
        f32x4 r;
#pragma unroll
        for (int j = 0; j < 4; ++j) r[j] = logf(acc[j]);
        ((f32x4*)gene_out)[base] = r;
    }
}

// ------------------------------- launcher ----------------------------------
// float ws region (floats)
#define OFF_QH_H  0
#define OFF_QH_S  131072
#define OFF_QH_A  262144
#define OFF_QSC   393216
#define OFF_GI    524288
#define OFF_GH    917504
#define OFF_HSC   1310720
#define OFF_STSC  1343488
#define OFF_ACSC  1344768
#define OFF_STLG  1346048
#define OFF_ACLG  1347328
#define ZERO_FLOATS 1348608
#define OFF_HSL   1348608
#define OFF_M     1381376
#define OFF_Z     1381504
#define OFF_COPY  1381632
#define FLOAT_TOTAL 6501632
// short region (shorts, offset from short base)
#define SO_HS     0
#define SO_SE     33554432
#define SO_AE     34865152
#define SO_Q0     36175872
#define SO_X      36306944
#define SO_HNB    36831232
#define SO_WQHT   36962304
#define SO_WQST   38010880
#define SO_WQAT   39059456
#define SO_WQSCT  40108032
#define SO_WMHT   41156608
#define SO_WMST   42205184
#define SO_WMAT   43253760
#define SO_WMSCT  44302336
#define SO_WIH    45350912
#define SO_WHH    57933824

extern "C" void kernel_launch(void* const* d_in, const int* in_sizes, int n_in,
                              void* d_out, int out_size, void* d_ws, size_t ws_size,
                              hipStream_t stream) {
    const float* inp     = (const float*)d_in[0];
    const float* hidden  = (const float*)d_in[1];
    const float* hs      = (const float*)d_in[2];
    const float* sprob   = (const float*)d_in[3];
    const float* se      = (const float*)d_in[4];
    const float* aprob   = (const float*)d_in[5];
    const float* ae      = (const float*)d_in[6];
    const int*   lens    = (const int*)d_in[7];
    const int*   hwi     = (const int*)d_in[8];
    const float* Wq_hist = (const float*)d_in[9];
    const float* bq_hist = (const float*)d_in[10];
    const float* Wm_hist = (const float*)d_in[11];
    const float* v_hist  = (const float*)d_in[12];
    const float* Wq_s    = (const float*)d_in[13];
    const float* bq_s    = (const float*)d_in[14];
    const float* Wm_s    = (const float*)d_in[15];
    const float* v_s     = (const float*)d_in[16];
    const float* Wq_a    = (const float*)d_in[17];
    const float* bq_a    = (const float*)d_in[18];
    const float* Wm_a    = (const float*)d_in[19];
    const float* v_a     = (const float*)d_in[20];
    const float* Wq_sc   = (const float*)d_in[21];
    const float* bq_sc   = (const float*)d_in[22];
    const float* Wm_sc   = (const float*)d_in[23];
    const float* v_sc    = (const float*)d_in[24];
    const float* W_ih    = (const float*)d_in[25];
    const float* W_hh    = (const float*)d_in[26];
    const float* b_ih    = (const float*)d_in[27];
    const float* b_hh    = (const float*)d_in[28];
    const float* W_out   = (const float*)d_in[29];
    const float* b_out   = (const float*)d_in[30];

    float* out  = (float*)d_out;
    float* w    = (float*)d_ws;
    float* hnew = out + BV;
    unsigned short* sb = (unsigned short*)(w + FLOAT_TOTAL);

    float* qh_h = w + OFF_QH_H;  float* qh_s = w + OFF_QH_S;  float* qh_a = w + OFF_QH_A;
    float* qsc  = w + OFF_QSC;   float* gi   = w + OFF_GI;    float* gh   = w + OFF_GH;
    float* hsc  = w + OFF_HSC;   float* stsc = w + OFF_STSC;  float* acsc = w + OFF_ACSC;
    float* stlg = w + OFF_STLG;  float* aclg = w + OFF_ACLG;
    float* hsl  = w + OFF_HSL;   float* mbuf = w + OFF_M;     float* zbuf = w + OFF_Z;
    float* copyp = w + OFF_COPY;

    unsigned short* hs_bf = sb + SO_HS;   unsigned short* se_bf = sb + SO_SE;
    unsigned short* ae_bf = sb + SO_AE;   unsigned short* q0_bf = sb + SO_Q0;
    unsigned short* x_bf  = sb + SO_X;    unsigned short* hnb   = sb + SO_HNB;
    unsigned short* WqhT  = sb + SO_WQHT; unsigned short* WqsT  = sb + SO_WQST;
    unsigned short* WqaT  = sb + SO_WQAT; unsigned short* WqscT = sb + SO_WQSCT;
    unsigned short* WmhT  = sb + SO_WMHT; unsigned short* WmsT  = sb + SO_WMST;
    unsigned short* WmaT  = sb + SO_WMAT; unsigned short* WmscT = sb + SO_WMSCT;
    unsigned short* WihB  = sb + SO_WIH;  unsigned short* WhhB  = sb + SO_WHH;

    dim3 blk(256);

    hipMemsetAsync(w, 0, (size_t)ZERO_FLOATS * 4, stream);
    hipMemsetAsync(copyp, 0, (size_t)BV * 4, stream);
    hipMemsetAsync(out, 0, (size_t)BV * 4, stream);

    // bf16 conversions
    k_cvt<<<dim3(16384), blk, 0, stream>>>(hs, hs_bf, 4194304);
    k_cvt<<<dim3(640),   blk, 0, stream>>>(se, se_bf, 163840);
    k_cvt<<<dim3(640),   blk, 0, stream>>>(ae, ae_bf, 163840);
    k_cvt<<<dim3(64),    blk, 0, stream>>>(hidden, q0_bf, 16384);
    k_cvt<<<dim3(6144),  blk, 0, stream>>>(W_ih, WihB, 1572864);
    k_cvt<<<dim3(1536),  blk, 0, stream>>>(W_hh, WhhB, 393216);
    TrArgs ta;
    ta.s[0]=Wq_hist; ta.s[1]=Wq_s; ta.s[2]=Wq_a; ta.s[3]=Wq_sc;
    ta.s[4]=Wm_hist; ta.s[5]=Wm_s; ta.s[6]=Wm_a; ta.s[7]=Wm_sc;
    ta.d[0]=WqhT; ta.d[1]=WqsT; ta.d[2]=WqaT; ta.d[3]=WqscT;
    ta.d[4]=WmhT; ta.d[5]=WmsT; ta.d[6]=WmaT; ta.d[7]=WmscT;
    k_trcvt<<<dim3(16, 16, 8), blk, 0, stream>>>(ta);

    // q-projections (split-K atomic, bias folded into consumers)
    k_qh4<<<dim3(8, 4, 3), blk, 0, stream>>>(q0_bf, WqhT, WqsT, WqaT, qh_h, qh_s, qh_a);
    // big hist MLP
    k_hist2<<<dim3(2048), blk, 0, stream>>>(hs_bf, WmhT, lens, qh_h, bq_hist, v_hist, hsc);
    // state/action score MLPs
    k_att3<<<dim3(8, 10, 2), blk, 0, stream>>>(se_bf, ae_bf, WmsT, WmaT, qh_s, qh_a, bq_s, bq_a, v_s, v_a, stsc, acsc);
    // contexts -> x (bf16)
    k_chis<<<dim3(128), blk, 0, stream>>>(hsc, lens, hs_bf, x_bf);
    k_assemble<<<dim3(128), blk, 0, stream>>>(inp, stsc, acsc, se_bf, ae_bf, x_bf);
    // GRU
    k_gigh2<<<dim3(24, 8, 2), blk, 0, stream>>>(x_bf, q0_bf, WihB, WhhB, gi, gh);
    k_gru<<<dim3(512), blk, 0, stream>>>(gi, gh, b_ih, b_hh, hidden, hnew, hnb);
    // copy-scorer query + gene logits
    k_qsc2<<<dim3(8, 2), blk, 0, stream>>>(hnb, WqscT, qsc);
    k_geneKN<<<dim3(313, 2), blk, 0, stream>>>(hnb, W_out, out);
    // hs / st / ac logits
    k_hsl<<<dim3(64, 128), blk, 0, stream>>>(hnew, hs_bf, hsl);
    k_stac3<<<dim3(8, 10, 2), blk, 0, stream>>>(se_bf, ae_bf, WmscT, Wm_sc + (size_t)1024 * 1024, qsc, bq_sc, v_sc, stlg, aclg);
    // softmax stats, scatter, fused final
    k_smstats<<<dim3(128), blk, 0, stream>>>(out, b_out, hsl, stlg, aclg, mbuf, zbuf);
    k_scatter<<<dim3(128), blk, 0, stream>>>(hsl, mbuf, zbuf, hwi, copyp);
    k_final<<<dim3(40, 128), blk, 0, stream>>>(out, b_out, copyp, sprob, aprob, stlg, aclg, mbuf, zbuf);

    (void)in_sizes; (void)n_in; (void)out_size; (void)ws_size;
}

// Round 3
// 591.172 us; speedup vs baseline: 1.7896x; 1.1041x over previous
//
#include <hip/hip_runtime.h>
#include <stdint.h>

typedef __attribute__((ext_vector_type(4))) float f32x4;
typedef __attribute__((ext_vector_type(2))) unsigned int u32x2;
typedef __attribute__((ext_vector_type(4))) unsigned int u32x4;
typedef __attribute__((ext_vector_type(8))) short bf16x8;

#define BV (128*40000)

__device__ __forceinline__ unsigned rne_bf16(float f) {
    unsigned x = __float_as_uint(f);
    return ((x + 0x7FFFu + ((x >> 16) & 1u)) >> 16) & 0xFFFFu;
}
__device__ __forceinline__ unsigned pack2(float a, float b) {
    return rne_bf16(a) | (rne_bf16(b) << 16);
}
__device__ __forceinline__ float bf2f(unsigned u) {
    return __uint_as_float((u & 0xFFFFu) << 16);
}
__device__ __forceinline__ float sigm(float x) { return 1.0f / (1.0f + expf(-x)); }

__device__ __forceinline__ void gload16(const void* g, void* l) {
    __builtin_amdgcn_global_load_lds(
        (const __attribute__((address_space(1))) unsigned*)g,
        (__attribute__((address_space(3))) unsigned*)l, 16, 0, 0);
}

// ---------------------------------------------------------------------------
// m97-style bf16 MFMA GEMM: 128x128 tile, BK=32, double-buffered LDS,
// global_load_lds staging (both operands bf16, Bt is N x K row-major).
// EPI 1: tanh-reduce:  atomicAdd(out[row], sum_col tanh(acc+rb[row/rpb][col]
//        +cb1[col](+cb2[col]))*v[col])
// EPI 2: atomicAdd(out[row*ldc+col], acc)   (split-K accumulate)
// ---------------------------------------------------------------------------
template<int EPI>
__device__ __forceinline__ void mgemm(
    const unsigned short* __restrict__ A, const unsigned short* __restrict__ Bt,
    float* __restrict__ out, const float* __restrict__ rb,
    const float* __restrict__ cb1, const float* __restrict__ cb2,
    const float* __restrict__ vvec,
    int m0, int n0, int kb, int ke, int ldk, int ldc, int rpb)
{
    __shared__ unsigned short As[2][4096];
    __shared__ unsigned short Bs[2][4096];
    const int t = threadIdx.x, lane = t & 63, wv = t >> 6;
    const int l16 = lane & 15, lq = lane >> 4;
    const int wm = wv >> 1, wn = wv & 1;

    const int srow = lane >> 2, scol = (lane & 3) << 3;
    const unsigned short* gA0 = A + (size_t)(m0 + (wv << 4) + srow) * ldk + kb + scol;
    const unsigned short* gA1 = gA0 + (size_t)64 * ldk;
    const unsigned short* gB0 = Bt + (size_t)(n0 + (wv << 4) + srow) * ldk + kb + scol;
    const unsigned short* gB1 = gB0 + (size_t)64 * ldk;
    unsigned short* lA0 = &As[0][wv << 9];
    unsigned short* lA1 = &As[0][(wv + 4) << 9];
    unsigned short* lB0 = &Bs[0][wv << 9];
    unsigned short* lB1 = &Bs[0][(wv + 4) << 9];

    f32x4 acc[4][4];
#pragma unroll
    for (int i = 0; i < 4; ++i)
#pragma unroll
        for (int j = 0; j < 4; ++j) acc[i][j] = (f32x4){0.f, 0.f, 0.f, 0.f};

    const int NS = (ke - kb) >> 5;
    gload16(gA0, lA0); gload16(gA1, lA1);
    gload16(gB0, lB0); gload16(gB1, lB1);

    for (int s = 0; s < NS; ++s) {
        __syncthreads();
        if (s + 1 < NS) {
            const int nb = (s + 1) & 1, ko = (s + 1) << 5;
            gload16(gA0 + ko, lA0 + (nb << 12)); gload16(gA1 + ko, lA1 + (nb << 12));
            gload16(gB0 + ko, lB0 + (nb << 12)); gload16(gB1 + ko, lB1 + (nb << 12));
        }
        const unsigned short* ab = As[s & 1];
        const unsigned short* bb = Bs[s & 1];
        bf16x8 af[4], bfv[4];
#pragma unroll
        for (int i = 0; i < 4; ++i)
            af[i] = *(const bf16x8*)(ab + (((wm << 6) + (i << 4) + l16) << 5) + (lq << 3));
#pragma unroll
        for (int i = 0; i < 4; ++i)
            bfv[i] = *(const bf16x8*)(bb + (((wn << 6) + (i << 4) + l16) << 5) + (lq << 3));
#pragma unroll
        for (int mf = 0; mf < 4; ++mf)
#pragma unroll
            for (int nf = 0; nf < 4; ++nf)
                acc[mf][nf] = __builtin_amdgcn_mfma_f32_16x16x32_bf16(af[mf], bfv[nf], acc[mf][nf], 0, 0, 0);
    }

    if (EPI == 1) {
#pragma unroll
        for (int mf = 0; mf < 4; ++mf) {
#pragma unroll
            for (int r = 0; r < 4; ++r) {
                int gr = m0 + (wm << 6) + (mf << 4) + (lq << 2) + r;
                const float* rbp = rb + (size_t)(gr / rpb) * 1024;
                float s = 0.0f;
#pragma unroll
                for (int nf = 0; nf < 4; ++nf) {
                    int gc = n0 + (wn << 6) + (nf << 4) + l16;
                    float xv = acc[mf][nf][r] + rbp[gc] + cb1[gc];
                    if (cb2) xv += cb2[gc];
                    s += tanhf(xv) * vvec[gc];
                }
#pragma unroll
                for (int msk = 1; msk < 16; msk <<= 1) s += __shfl_xor(s, msk, 64);
                if (l16 == 0) atomicAdd(&out[gr], s);
            }
        }
    } else {
#pragma unroll
        for (int mf = 0; mf < 4; ++mf) {
            int gr0 = m0 + (wm << 6) + (mf << 4) + (lq << 2);
#pragma unroll
            for (int nf = 0; nf < 4; ++nf) {
                int gc = n0 + (wn << 6) + (nf << 4) + l16;
#pragma unroll
                for (int r = 0; r < 4; ++r)
                    atomicAdd(&out[(size_t)(gr0 + r) * ldc + gc], acc[mf][nf][r]);
            }
        }
    }
}

// gene logits body: A = hnew bf16 (gload_lds), B = W_out f32 KxN (reg-stage
// cvt), full K=1024, plain store with fused bias.
__device__ __forceinline__ void gene_body(
    const unsigned short* __restrict__ hnb, const float* __restrict__ Wout,
    const float* __restrict__ b_out, float* __restrict__ out, int n0)
{
    __shared__ unsigned short As[2][4096];
    __shared__ unsigned short Bs[2][4096];
    const int t = threadIdx.x, lane = t & 63, wv = t >> 6;
    const int l16 = lane & 15, lq = lane >> 4;
    const int wm = wv >> 1, wn = wv & 1;

    const int srow = lane >> 2, scol = (lane & 3) << 3;
    const unsigned short* gA0 = hnb + (size_t)((wv << 4) + srow) * 1024 + scol;
    const unsigned short* gA1 = gA0 + (size_t)64 * 1024;
    unsigned short* lA0 = &As[0][wv << 9];
    unsigned short* lA1 = &As[0][(wv + 4) << 9];

    const int bn = t & 127, kh = t >> 7;
    const bool ok = (n0 + bn) < 40000;
    const float* gB = Wout + (size_t)(kh * 16) * 40000 + (n0 + bn);

    f32x4 acc[4][4];
#pragma unroll
    for (int i = 0; i < 4; ++i)
#pragma unroll
        for (int j = 0; j < 4; ++j) acc[i][j] = (f32x4){0.f, 0.f, 0.f, 0.f};

    auto stageB = [&](int buf, int ko) {
        const float* src = gB + (size_t)ko * 40000;
        float f[16];
#pragma unroll
        for (int j = 0; j < 16; ++j) f[j] = ok ? src[(size_t)j * 40000] : 0.0f;
        u32x4* d = (u32x4*)&Bs[buf][bn * 32 + kh * 16];
        d[0] = (u32x4){pack2(f[0],f[1]), pack2(f[2],f[3]), pack2(f[4],f[5]), pack2(f[6],f[7])};
        d[1] = (u32x4){pack2(f[8],f[9]), pack2(f[10],f[11]), pack2(f[12],f[13]), pack2(f[14],f[15])};
    };

    gload16(gA0, lA0); gload16(gA1, lA1); stageB(0, 0);
    for (int s = 0; s < 32; ++s) {
        __syncthreads();
        if (s + 1 < 32) {
            const int nb = (s + 1) & 1, ko = (s + 1) << 5;
            gload16(gA0 + ko, lA0 + (nb << 12)); gload16(gA1 + ko, lA1 + (nb << 12));
            stageB(nb, ko);
        }
        const unsigned short* ab = As[s & 1];
        const unsigned short* bb = Bs[s & 1];
        bf16x8 af[4], bfv[4];
#pragma unroll
        for (int i = 0; i < 4; ++i)
            af[i] = *(const bf16x8*)(ab + (((wm << 6) + (i << 4) + l16) << 5) + (lq << 3));
#pragma unroll
        for (int i = 0; i < 4; ++i)
            bfv[i] = *(const bf16x8*)(bb + (((wn << 6) + (i << 4) + l16) << 5) + (lq << 3));
#pragma unroll
        for (int mf = 0; mf < 4; ++mf)
#pragma unroll
            for (int nf = 0; nf < 4; ++nf)
                acc[mf][nf] = __builtin_amdgcn_mfma_f32_16x16x32_bf16(af[mf], bfv[nf], acc[mf][nf], 0, 0, 0);
    }
#pragma unroll
    for (int mf = 0; mf < 4; ++mf) {
        int gr0 = (wm << 6) + (mf << 4) + (lq << 2);
#pragma unroll
        for (int nf = 0; nf < 4; ++nf) {
            int gc = n0 + (wn << 6) + (nf << 4) + l16;
            if (gc < 40000) {
                float bo = b_out[gc];
#pragma unroll
                for (int r = 0; r < 4; ++r)
                    out[(size_t)(gr0 + r) * 40000 + gc] = acc[mf][nf][r] + bo;
            }
        }
    }
}

// ------------------------------ GEMM wrappers ------------------------------
// hist (2048 blocks) + state/action score MLPs (160 blocks) in one launch
__global__ __launch_bounds__(256) void k_hist_att(
    const unsigned short* hs, const unsigned short* WmhT, const int* lens,
    const float* qh_h, const float* bq_h, const float* v_h, float* hsc,
    const unsigned short* se, const unsigned short* ae,
    const unsigned short* WmsT, const unsigned short* WmaT,
    const float* qh_s, const float* qh_a, const float* bq_s, const float* bq_a,
    const float* v_s, const float* v_a, float* stsc, float* acsc) {
    int id = blockIdx.x;
    if (id < 2048) {
        int p = id & 255, n = id >> 8;      // XCD swizzle: n-siblings share XCD
        int b = p >> 1, l0 = (p & 1) << 7;
        if (lens[b] <= l0) return;          // fully-masked row block
        mgemm<1>(hs, WmhT, hsc, qh_h, bq_h, nullptr, v_h, p << 7, n << 7, 0, 1024, 1024, 0, 256);
    } else {
        int r = id - 2048;                  // 0..159
        int z = r / 80; r -= z * 80;
        int y = r >> 3, x = r & 7;
        if (z == 0)
            mgemm<1>(se, WmsT, stsc, qh_s, bq_s, nullptr, v_s, y * 128, x * 128, 0, 1024, 1024, 0, 10);
        else
            mgemm<1>(ae, WmaT, acsc, qh_a, bq_a, nullptr, v_a, y * 128, x * 128, 0, 1024, 1024, 0, 10);
    }
}

__global__ __launch_bounds__(256) void k_stac3(
    const unsigned short* se, const unsigned short* ae, const unsigned short* WmscT,
    const float* tagrow, const float* qsc, const float* bq_sc, const float* v_sc,
    float* stlg, float* aclg) {
    if (blockIdx.z == 0)
        mgemm<1>(se, WmscT, stlg, qsc, bq_sc, nullptr, v_sc, blockIdx.y * 128, blockIdx.x * 128, 0, 1024, 1024, 0, 10);
    else
        mgemm<1>(ae, WmscT, aclg, qsc, bq_sc, tagrow, v_sc, blockIdx.y * 128, blockIdx.x * 128, 0, 1024, 1024, 0, 10);
}

__global__ __launch_bounds__(256) void k_qh4(
    const unsigned short* q0, const unsigned short* W0, const unsigned short* W1,
    const unsigned short* W2, float* o0, float* o1, float* o2) {
    const unsigned short* W = W0; float* o = o0;
    if (blockIdx.z == 1) { W = W1; o = o1; }
    if (blockIdx.z == 2) { W = W2; o = o2; }
    int kb = blockIdx.y << 8;
    mgemm<2>(q0, W, o, nullptr, nullptr, nullptr, nullptr, 0, blockIdx.x * 128, kb, kb + 256, 1024, 1024, 1);
}

__global__ __launch_bounds__(256) void k_gigh2(
    const unsigned short* xb, const unsigned short* q0,
    const unsigned short* Wih, const unsigned short* Whh, float* gi, float* gh) {
    if (blockIdx.z == 0) {
        int kb = blockIdx.y << 9;
        mgemm<2>(xb, Wih, gi, nullptr, nullptr, nullptr, nullptr, 0, blockIdx.x * 128, kb, kb + 512, 4096, 3072, 1);
    } else {
        if (blockIdx.y >= 2) return;
        int kb = blockIdx.y << 9;
        mgemm<2>(q0, Whh, gh, nullptr, nullptr, nullptr, nullptr, 0, blockIdx.x * 128, kb, kb + 512, 1024, 3072, 1);
    }
}

// qsc (16 blocks, split-K 2) + gene logits (313 blocks) in one launch
__global__ __launch_bounds__(256) void k_qsc_gene(
    const unsigned short* hnb, const unsigned short* WqscT, float* qsc,
    const float* Wout, const float* b_out, float* out) {
    int id = blockIdx.x;
    if (id < 16) {
        int x = id & 7, kb = (id >> 3) << 9;
        mgemm<2>(hnb, WqscT, qsc, nullptr, nullptr, nullptr, nullptr, 0, x * 128, kb, kb + 512, 1024, 1024, 1);
    } else {
        gene_body(hnb, Wout, b_out, out, (id - 16) << 7);
    }
}

// --------------------------- prep kernels -----------------------------------
struct CvtArgs { const float* s[6]; unsigned short* d[6]; int pre[7]; };
__global__ __launch_bounds__(256) void k_cvt_all(CvtArgs a) {
    int total = a.pre[6];
    for (int i = blockIdx.x * 256 + threadIdx.x; i < total; i += gridDim.x * 256) {
        int seg = 0;
        while (i >= a.pre[seg + 1]) ++seg;
        int loc = i - a.pre[seg];
        const f32x4* s4 = (const f32x4*)a.s[seg] + (size_t)loc * 2;
        f32x4 q0 = s4[0], q1 = s4[1];
        ((u32x4*)a.d[seg])[loc] =
            (u32x4){pack2(q0[0],q0[1]), pack2(q0[2],q0[3]), pack2(q1[0],q1[1]), pack2(q1[2],q1[3])};
    }
}

struct TrArgs { const float* s[8]; unsigned short* d[8]; };
__global__ __launch_bounds__(256) void k_trcvt(TrArgs a) {
    __shared__ float tile[64][65];
    const float* in = a.s[blockIdx.z];
    unsigned short* ot = a.d[blockIdx.z];
    int k0 = blockIdx.y << 6, n0 = blockIdx.x << 6;
    int tr = threadIdx.x >> 6, tc = threadIdx.x & 63;
#pragma unroll
    for (int i = 0; i < 16; ++i) {
        int r = (i << 2) + tr;
        tile[r][tc] = in[(size_t)(k0 + r) * 1024 + n0 + tc];
    }
    __syncthreads();
#pragma unroll
    for (int i = 0; i < 16; ++i) {
        int r = (i << 2) + tr;
        ot[(size_t)(n0 + r) * 1024 + k0 + tc] = (unsigned short)rne_bf16(tile[tc][r]);
    }
}

// --------------------------- non-GEMM kernels ------------------------------
__device__ __forceinline__ void softmax10(const float* src, float* dst) {
    float m = src[0];
    for (int i = 1; i < 10; ++i) m = fmaxf(m, src[i]);
    float z = 0.f, e[10];
    for (int i = 0; i < 10; ++i) { e[i] = expf(src[i] - m); z += e[i]; }
    float iz = 1.0f / z;
    for (int i = 0; i < 10; ++i) dst[i] = e[i] * iz;
}

// hist softmax + c_his, inp copy, state/action softmax + contexts -> x (bf16)
__global__ __launch_bounds__(256) void k_ctx(
    const float* __restrict__ scores, const int* __restrict__ lens,
    const unsigned short* __restrict__ hs,
    const float* __restrict__ inp, const float* __restrict__ st_sc, const float* __restrict__ ac_sc,
    const unsigned short* __restrict__ se, const unsigned short* __restrict__ ae,
    unsigned short* __restrict__ xb) {
    int b = blockIdx.x, t = threadIdx.x;
    __shared__ float w[256];
    __shared__ float red[256];
    __shared__ float sw[10], aw[10];
    // --- hist masked softmax ---
    int len = lens[b];
    float s = scores[b * 256 + t];
    bool valid = t < len;
    red[t] = valid ? s : -3.0e38f;
    __syncthreads();
    for (int st = 128; st > 0; st >>= 1) { if (t < st) red[t] = fmaxf(red[t], red[t + st]); __syncthreads(); }
    float m = red[0];
    __syncthreads();
    float e = valid ? expf(s - m) : 0.0f;
    red[t] = e;
    __syncthreads();
    for (int st = 128; st > 0; st >>= 1) { if (t < st) red[t] += red[t + st]; __syncthreads(); }
    float Z = red[0];
    __syncthreads();
    w[t] = e / Z;
    if (t == 0) softmax10(st_sc + b * 10, sw);
    if (t == 64) softmax10(ac_sc + b * 10, aw);
    // --- inp copy ---
    f32x4 iv = ((const f32x4*)(inp + (size_t)b * 1024))[t];
    *((u32x2*)(xb + (size_t)b * 4096) + t) = (u32x2){pack2(iv[0], iv[1]), pack2(iv[2], iv[3])};
    __syncthreads();
    // --- c_his ---
    float a0 = 0.f, a1 = 0.f, a2 = 0.f, a3 = 0.f;
    for (int l = 0; l < 256; ++l) {
        float wl = w[l];
        if (wl == 0.0f) continue;
        u32x2 u = *((const u32x2*)(hs + ((size_t)b * 256 + l) * 1024) + t);
        a0 += wl * bf2f(u[0]); a1 += wl * bf2f(u[0] >> 16);
        a2 += wl * bf2f(u[1]); a3 += wl * bf2f(u[1] >> 16);
    }
    *((u32x2*)(xb + (size_t)b * 4096 + 1024) + t) = (u32x2){pack2(a0, a1), pack2(a2, a3)};
    // --- c_state / c_action ---
    float cs0=0,cs1=0,cs2=0,cs3=0, ca0=0,ca1=0,ca2=0,ca3=0;
#pragma unroll
    for (int q = 0; q < 10; ++q) {
        u32x2 us = *((const u32x2*)(se + ((size_t)b * 10 + q) * 1024) + t);
        u32x2 ua = *((const u32x2*)(ae + ((size_t)b * 10 + q) * 1024) + t);
        float ws = sw[q], wa = aw[q];
        cs0 += ws * bf2f(us[0]); cs1 += ws * bf2f(us[0] >> 16);
        cs2 += ws * bf2f(us[1]); cs3 += ws * bf2f(us[1] >> 16);
        ca0 += wa * bf2f(ua[0]); ca1 += wa * bf2f(ua[0] >> 16);
        ca2 += wa * bf2f(ua[1]); ca3 += wa * bf2f(ua[1] >> 16);
    }
    *((u32x2*)(xb + (size_t)b * 4096 + 2048) + t) = (u32x2){pack2(cs0, cs1), pack2(cs2, cs3)};
    *((u32x2*)(xb + (size_t)b * 4096 + 3072) + t) = (u32x2){pack2(ca0, ca1), pack2(ca2, ca3)};
}

// GRU elementwise + hs_logits (h_new . hs_vectors) fused; one block per b
__global__ __launch_bounds__(1024) void k_gruhsl(
    const float* __restrict__ gi, const float* __restrict__ gh,
    const float* __restrict__ b_ih, const float* __restrict__ b_hh,
    const float* __restrict__ h0, float* __restrict__ hnew,
    unsigned short* __restrict__ hnb,
    const unsigned short* __restrict__ hs, float* __restrict__ hsl) {
    int b = blockIdx.x, j = threadIdx.x;
    size_t i = (size_t)b * 1024 + j;
    const float* gib = gi + (size_t)b * 3072;
    const float* ghb = gh + (size_t)b * 3072;
    float r = sigm(gib[j] + b_ih[j] + ghb[j] + b_hh[j]);
    float z = sigm(gib[1024 + j] + b_ih[1024 + j] + ghb[1024 + j] + b_hh[1024 + j]);
    float hn = ghb[2048 + j] + b_hh[2048 + j];
    float n = tanhf(gib[2048 + j] + b_ih[2048 + j] + r * hn);
    float h = (1.0f - z) * n + z * h0[i];
    hnew[i] = h;
    hnb[i] = (unsigned short)rne_bf16(h);
    __shared__ float hsm[1024];
    hsm[j] = h;
    __syncthreads();
    int wave = j >> 6, lane = j & 63;
    float hr[16];
#pragma unroll
    for (int k = 0; k < 16; ++k) hr[k] = hsm[lane * 16 + k];
    for (int l = wave; l < 256; l += 16) {
        const u32x4* row = (const u32x4*)(hs + ((size_t)b * 256 + l) * 1024);
        u32x4 u0 = row[lane * 2], u1 = row[lane * 2 + 1];
        float s = hr[0]*bf2f(u0[0]) + hr[1]*bf2f(u0[0]>>16) + hr[2]*bf2f(u0[1]) + hr[3]*bf2f(u0[1]>>16)
                + hr[4]*bf2f(u0[2]) + hr[5]*bf2f(u0[2]>>16) + hr[6]*bf2f(u0[3]) + hr[7]*bf2f(u0[3]>>16)
                + hr[8]*bf2f(u1[0]) + hr[9]*bf2f(u1[0]>>16) + hr[10]*bf2f(u1[1]) + hr[11]*bf2f(u1[1]>>16)
                + hr[12]*bf2f(u1[2]) + hr[13]*bf2f(u1[2]>>16) + hr[14]*bf2f(u1[3]) + hr[15]*bf2f(u1[3]>>16);
#pragma unroll
        for (int msk = 1; msk < 64; msk <<= 1) s += __shfl_xor(s, msk, 64);
        if (lane == 0) hsl[b * 256 + l] = s;
    }
}

// softmax stats over concat[gene(40000,+bias baked) | hs(256) | st(10) | ac(10)]
// + copy_p scatter; one block per b
__global__ __launch_bounds__(256) void k_smsc(
    const float* __restrict__ gene, const float* __restrict__ hsl,
    const float* __restrict__ stl, const float* __restrict__ acl,
    const int* __restrict__ hwi,
    float* __restrict__ mbuf, float* __restrict__ zbuf, float* __restrict__ copyp) {
    int b = blockIdx.x, t = threadIdx.x;
    __shared__ float red[256];
    const f32x4* g4 = (const f32x4*)(gene + (size_t)b * 40000);
    float mx = -3.0e38f;
    for (int i = t; i < 10000; i += 256) {
        f32x4 q = g4[i];
        mx = fmaxf(mx, fmaxf(fmaxf(q[0], q[1]), fmaxf(q[2], q[3])));
    }
    float hv = hsl[b * 256 + t];
    mx = fmaxf(mx, hv);
    if (t < 10) mx = fmaxf(mx, fmaxf(stl[b * 10 + t], acl[b * 10 + t]));
    red[t] = mx; __syncthreads();
    for (int s = 128; s > 0; s >>= 1) { if (t < s) red[t] = fmaxf(red[t], red[t + s]); __syncthreads(); }
    float m = red[0];
    __syncthreads();
    float sum = 0.f;
    for (int i = t; i < 10000; i += 256) {
        f32x4 q = g4[i];
        sum += expf(q[0]-m) + expf(q[1]-m) + expf(q[2]-m) + expf(q[3]-m);
    }
    sum += expf(hv - m);
    if (t < 10) sum += expf(stl[b * 10 + t] - m) + expf(acl[b * 10 + t] - m);
    red[t] = sum; __syncthreads();
    for (int s = 128; s > 0; s >>= 1) { if (t < s) red[t] += red[t + s]; __syncthreads(); }
    float Z = red[0];
    if (t == 0) { mbuf[b] = m; zbuf[b] = Z; }
    float wv = expf(hv - m) / Z;
    atomicAdd(copyp + (size_t)b * 40000 + hwi[b * 256 + t], wv);
}

__global__ __launch_bounds__(256) void k_final(
    float* __restrict__ gene_out, const float* __restrict__ copyp,
    const float* __restrict__ sprob, const float* __restrict__ aprob,
    const float* __restrict__ stl, const float* __restrict__ acl,
    const float* __restrict__ mbuf, const float* __restrict__ zbuf) {
    int b = blockIdx.y, t = threadIdx.x;
    __shared__ float sw[10], aw[10];
    float m = mbuf[b], iz = 1.0f / zbuf[b];
    if (t < 10) sw[t] = expf(stl[b * 10 + t] - m) * iz;
    if (t >= 64 && t < 74) aw[t - 64] = expf(acl[b * 10 + (t - 64)] - m) * iz;
    __syncthreads();
    int v4 = blockIdx.x * 256 + t;
    if (v4 < 10000) {
        size_t base = (size_t)b * 10000 + v4;
        f32x4 g = ((const f32x4*)gene_out)[base];
        f32x4 c = ((const f32x4*)copyp)[base];
        f32x4 acc;
#pragma unroll
        for (int j = 0; j < 4; ++j) acc[j] = expf(g[j] - m) * iz + c[j];
#pragma unroll
        for (int s = 0; s < 10; ++s) {
            f32x4 pv = ((const f32x4*)sprob)[((size_t)b * 10 + s) * 10000 + v4];
            f32x4 av = ((const f32x4*)aprob)[((size_t)b * 10 + s) * 10000 + v4];
            float ws = sw[s], wa = aw[s];
#pragma unroll
            for (int j = 0; j < 4; ++j) acc[j] += ws * pv[j] + wa * av[j];
        }
        f32x4 r;
#pragma unroll
        for (int j = 0; j < 4; ++j) r[j] = logf(acc[j]);
        ((f32x4*)gene_out)[base] = r;
    }
}

// ------------------------------- launcher ----------------------------------
// float ws region (floats)
#define OFF_QH_H  0
#define OFF_QH_S  131072
#define OFF_QH_A  262144
#define OFF_QSC   393216
#define OFF_GI    524288
#define OFF_GH    917504
#define OFF_HSC   1310720
#define OFF_STSC  1343488
#define OFF_ACSC  1344768
#define OFF_STLG  1346048
#define OFF_ACLG  1347328
#define ZERO_FLOATS 1348608
#define OFF_HSL   1348608
#define OFF_M     1381376
#define OFF_Z     1381504
#define OFF_COPY  1381632
#define FLOAT_TOTAL 6501632
// short region (shorts, offset from short base)
#define SO_HS     0
#define SO_SE     33554432
#define SO_AE     34865152
#define SO_Q0     36175872
#define SO_X      36306944
#define SO_HNB    36831232
#define SO_WQHT   36962304
#define SO_WQST   38010880
#define SO_WQAT   39059456
#define SO_WQSCT  40108032
#define SO_WMHT   41156608
#define SO_WMST   42205184
#define SO_WMAT   43253760
#define SO_WMSCT  44302336
#define SO_WIH    45350912
#define SO_WHH    57933824

extern "C" void kernel_launch(void* const* d_in, const int* in_sizes, int n_in,
                              void* d_out, int out_size, void* d_ws, size_t ws_size,
                              hipStream_t stream) {
    const float* inp     = (const float*)d_in[0];
    const float* hidden  = (const float*)d_in[1];
    const float* hs      = (const float*)d_in[2];
    const float* sprob   = (const float*)d_in[3];
    const float* se      = (const float*)d_in[4];
    const float* aprob   = (const float*)d_in[5];
    const float* ae      = (const float*)d_in[6];
    const int*   lens    = (const int*)d_in[7];
    const int*   hwi     = (const int*)d_in[8];
    const float* Wq_hist = (const float*)d_in[9];
    const float* bq_hist = (const float*)d_in[10];
    const float* Wm_hist = (const float*)d_in[11];
    const float* v_hist  = (const float*)d_in[12];
    const float* Wq_s    = (const float*)d_in[13];
    const float* bq_s    = (const float*)d_in[14];
    const float* Wm_s    = (const float*)d_in[15];
    const float* v_s     = (const float*)d_in[16];
    const float* Wq_a    = (const float*)d_in[17];
    const float* bq_a    = (const float*)d_in[18];
    const float* Wm_a    = (const float*)d_in[19];
    const float* v_a     = (const float*)d_in[20];
    const float* Wq_sc   = (const float*)d_in[21];
    const float* bq_sc   = (const float*)d_in[22];
    const float* Wm_sc   = (const float*)d_in[23];
    const float* v_sc    = (const float*)d_in[24];
    const float* W_ih    = (const float*)d_in[25];
    const float* W_hh    = (const float*)d_in[26];
    const float* b_ih    = (const float*)d_in[27];
    const float* b_hh    = (const float*)d_in[28];
    const float* W_out   = (const float*)d_in[29];
    const float* b_out   = (const float*)d_in[30];

    float* out  = (float*)d_out;
    float* w    = (float*)d_ws;
    float* hnew = out + BV;
    unsigned short* sb = (unsigned short*)(w + FLOAT_TOTAL);

    float* qh_h = w + OFF_QH_H;  float* qh_s = w + OFF_QH_S;  float* qh_a = w + OFF_QH_A;
    float* qsc  = w + OFF_QSC;   float* gi   = w + OFF_GI;    float* gh   = w + OFF_GH;
    float* hsc  = w + OFF_HSC;   float* stsc = w + OFF_STSC;  float* acsc = w + OFF_ACSC;
    float* stlg = w + OFF_STLG;  float* aclg = w + OFF_ACLG;
    float* hsl  = w + OFF_HSL;   float* mbuf = w + OFF_M;     float* zbuf = w + OFF_Z;
    float* copyp = w + OFF_COPY;

    unsigned short* hs_bf = sb + SO_HS;   unsigned short* se_bf = sb + SO_SE;
    unsigned short* ae_bf = sb + SO_AE;   unsigned short* q0_bf = sb + SO_Q0;
    unsigned short* x_bf  = sb + SO_X;    unsigned short* hnb   = sb + SO_HNB;
    unsigned short* WqhT  = sb + SO_WQHT; unsigned short* WqsT  = sb + SO_WQST;
    unsigned short* WqaT  = sb + SO_WQAT; unsigned short* WqscT = sb + SO_WQSCT;
    unsigned short* WmhT  = sb + SO_WMHT; unsigned short* WmsT  = sb + SO_WMST;
    unsigned short* WmaT  = sb + SO_WMAT; unsigned short* WmscT = sb + SO_WMSCT;
    unsigned short* WihB  = sb + SO_WIH;  unsigned short* WhhB  = sb + SO_WHH;

    dim3 blk(256);

    hipMemsetAsync(w, 0, (size_t)ZERO_FLOATS * 4, stream);
    hipMemsetAsync(copyp, 0, (size_t)BV * 4, stream);

    // bf16 conversions (one kernel)
    CvtArgs ca;
    ca.s[0]=hs; ca.s[1]=se; ca.s[2]=ae; ca.s[3]=hidden; ca.s[4]=W_ih; ca.s[5]=W_hh;
    ca.d[0]=hs_bf; ca.d[1]=se_bf; ca.d[2]=ae_bf; ca.d[3]=q0_bf; ca.d[4]=WihB; ca.d[5]=WhhB;
    ca.pre[0]=0; ca.pre[1]=4194304; ca.pre[2]=4358144; ca.pre[3]=4521984;
    ca.pre[4]=4538368; ca.pre[5]=6111232; ca.pre[6]=6504448;
    k_cvt_all<<<dim3(4096), blk, 0, stream>>>(ca);

    TrArgs ta;
    ta.s[0]=Wq_hist; ta.s[1]=Wq_s; ta.s[2]=Wq_a; ta.s[3]=Wq_sc;
    ta.s[4]=Wm_hist; ta.s[5]=Wm_s; ta.s[6]=Wm_a; ta.s[7]=Wm_sc;
    ta.d[0]=WqhT; ta.d[1]=WqsT; ta.d[2]=WqaT; ta.d[3]=WqscT;
    ta.d[4]=WmhT; ta.d[5]=WmsT; ta.d[6]=WmaT; ta.d[7]=WmscT;
    k_trcvt<<<dim3(16, 16, 8), blk, 0, stream>>>(ta);

    // q-projections (split-K atomic, bias folded into consumers)
    k_qh4<<<dim3(8, 4, 3), blk, 0, stream>>>(q0_bf, WqhT, WqsT, WqaT, qh_h, qh_s, qh_a);
    // big hist MLP + state/action score MLPs (one launch)
    k_hist_att<<<dim3(2208), blk, 0, stream>>>(hs_bf, WmhT, lens, qh_h, bq_hist, v_hist, hsc,
                                               se_bf, ae_bf, WmsT, WmaT, qh_s, qh_a, bq_s, bq_a,
                                               v_s, v_a, stsc, acsc);
    // contexts -> x (bf16)
    k_ctx<<<dim3(128), blk, 0, stream>>>(hsc, lens, hs_bf, inp, stsc, acsc, se_bf, ae_bf, x_bf);
    // GRU gates
    k_gigh2<<<dim3(24, 8, 2), blk, 0, stream>>>(x_bf, q0_bf, WihB, WhhB, gi, gh);
    // GRU elementwise + hs logits
    k_gruhsl<<<dim3(128), dim3(1024), 0, stream>>>(gi, gh, b_ih, b_hh, hidden, hnew, hnb, hs_bf, hsl);
    // copy-scorer query + gene logits (one launch; bias fused into store)
    k_qsc_gene<<<dim3(329), blk, 0, stream>>>(hnb, WqscT, qsc, W_out, b_out, out);
    // st / ac logits
    k_stac3<<<dim3(8, 10, 2), blk, 0, stream>>>(se_bf, ae_bf, WmscT, Wm_sc + (size_t)1024 * 1024,
                                                qsc, bq_sc, v_sc, stlg, aclg);
    // softmax stats + scatter, then fused final
    k_smsc<<<dim3(128), blk, 0, stream>>>(out, hsl, stlg, aclg, hwi, mbuf, zbuf, copyp);
    k_final<<<dim3(40, 128), blk, 0, stream>>>(out, copyp, sprob, aprob, stlg, aclg, mbuf, zbuf);

    (void)in_sizes; (void)n_in; (void)out_size; (void)ws_size;
}

// Round 4
// 575.351 us; speedup vs baseline: 1.8388x; 1.0275x over previous
//
#include <hip/hip_runtime.h>
#include <stdint.h>

typedef __attribute__((ext_vector_type(4))) float f32x4;
typedef __attribute__((ext_vector_type(2))) unsigned int u32x2;
typedef __attribute__((ext_vector_type(4))) unsigned int u32x4;
typedef __attribute__((ext_vector_type(8))) short bf16x8;

#define BV (128*40000)

__device__ __forceinline__ unsigned rne_bf16(float f) {
    unsigned x = __float_as_uint(f);
    return ((x + 0x7FFFu + ((x >> 16) & 1u)) >> 16) & 0xFFFFu;
}
__device__ __forceinline__ unsigned pack2(float a, float b) {
    return rne_bf16(a) | (rne_bf16(b) << 16);
}
__device__ __forceinline__ float bf2f(unsigned u) {
    return __uint_as_float((u & 0xFFFFu) << 16);
}
__device__ __forceinline__ float sigm(float x) { return 1.0f / (1.0f + expf(-x)); }
__device__ __forceinline__ float ftanh(float x) {
    float e = __expf(2.0f * x);
    return 1.0f - 2.0f / (e + 1.0f);
}

__device__ __forceinline__ void gload16(const void* g, void* l) {
    __builtin_amdgcn_global_load_lds(
        (const __attribute__((address_space(1))) unsigned*)g,
        (__attribute__((address_space(3))) unsigned*)l, 16, 0, 0);
}

// ---------------------------------------------------------------------------
// 256x256-tile bf16 MFMA GEMM with counted-vmcnt double-buffered pipeline.
// 512 threads = 8 waves (2M x 4N), wave tile 128x64, BK=64, LDS 128 KiB.
// XOR chunk swizzle (cc ^= row&7) applied on global source AND ds_read.
// Epilogue: tanh-reduce with per-16-row dead-frag skip (masked hist rows).
// ---------------------------------------------------------------------------
struct BigArgs {
    const unsigned short *hs, *WmhT, *se, *ae, *WmsT, *WmaT;
    const int* lens;
    const float *qh_h, *bq_h, *v_h;
    const float *qh_s, *bq_s, *v_s;
    const float *qh_a, *bq_a, *v_a;
    float *hsc, *stsc, *acsc;
};

__global__ __launch_bounds__(512, 1) void k_big(BigArgs a) {
    __shared__ unsigned short As[2][16384];
    __shared__ unsigned short Bs[2][16384];

    int bid = blockIdx.x;
    int wg = (bid & 7) * 69 + (bid >> 3);     // bijective XCD swizzle (552 = 8*69)

    const unsigned short *A, *Bt;
    const float *rb, *cb, *vv;
    float* out;
    int m0, n0, vrows, rpb;
    if (wg < 512) {
        int m = wg >> 2, n = wg & 3;
        A = a.hs; Bt = a.WmhT; rb = a.qh_h; cb = a.bq_h; vv = a.v_h; out = a.hsc;
        m0 = m << 8; n0 = n << 8; vrows = a.lens[m]; rpb = 256;
    } else {
        int r = wg - 512;
        int op = r / 20; r -= op * 20;
        int mt = r >> 2, nt = r & 3;
        if (op == 0) { A = a.se; Bt = a.WmsT; rb = a.qh_s; cb = a.bq_s; vv = a.v_s; out = a.stsc; }
        else         { A = a.ae; Bt = a.WmaT; rb = a.qh_a; cb = a.bq_a; vv = a.v_a; out = a.acsc; }
        m0 = mt << 8; n0 = nt << 8; vrows = 256; rpb = 10;
    }

    const int t = threadIdx.x, lane = t & 63, wv = t >> 6;
    const int l16 = lane & 15, lq = lane >> 4;
    const int wm = wv >> 2, wn = wv & 3;

    // staging: thread t covers chunk (row = srowL(+h*128+r*64), cc = t&7),
    // global source column pre-swizzled: gcc = (t&7) ^ (srowL&7)
    const int srowL = t >> 3;
    const int gccA = ((t & 7) ^ (srowL & 7)) << 3;
    const unsigned short* gA = A + (size_t)(m0 + srowL) * 1024 + gccA;
    const unsigned short* gB = Bt + (size_t)(n0 + srowL) * 1024 + gccA;

    f32x4 acc[8][4];
#pragma unroll
    for (int i = 0; i < 8; ++i)
#pragma unroll
        for (int j = 0; j < 4; ++j) acc[i][j] = (f32x4){0.f, 0.f, 0.f, 0.f};

    // ds_read swizzle constants (col&7 == l16&7 for both A and B frags)
    const int sw = l16 & 7;
    const int c0 = ((lq ^ sw) << 3);          // ks=0 chunk; ks=1 = c0^32
    const int A0 = (wm << 13) + (l16 << 6);
    const int B0 = ((wn >> 1) << 13) + ((((wn & 1) << 6) + l16) << 6);

#define STAGE(kt, d)                                                          \
    {                                                                         \
        const unsigned short* ga_ = gA + (size_t)(kt) * 64;                   \
        const unsigned short* gb_ = gB + (size_t)(kt) * 64;                   \
        _Pragma("unroll")                                                     \
        for (int h_ = 0; h_ < 2; ++h_) {                                      \
            _Pragma("unroll")                                                 \
            for (int r_ = 0; r_ < 2; ++r_) {                                  \
                size_t go_ = (size_t)(h_ * 128 + r_ * 64) * 1024;             \
                int lo_ = h_ * 8192 + r_ * 4096 + (wv << 9);                  \
                gload16(ga_ + go_, &As[d][lo_]);                              \
                gload16(gb_ + go_, &Bs[d][lo_]);                              \
            }                                                                 \
        }                                                                     \
    }

    STAGE(0, 0);
    for (int kt = 0; kt < 16; ++kt) {
        int cur = kt & 1;
        if (kt < 15) {
            STAGE(kt + 1, cur ^ 1);
            asm volatile("s_waitcnt vmcnt(8)" ::: "memory");
        } else {
            asm volatile("s_waitcnt vmcnt(0)" ::: "memory");
        }
        __builtin_amdgcn_s_barrier();
        __builtin_amdgcn_sched_barrier(0);

        const unsigned short* ab = As[cur];
        const unsigned short* bb = Bs[cur];
        if (vrows > (wm << 7)) {
            bf16x8 bf[4][2];
#pragma unroll
            for (int nf = 0; nf < 4; ++nf) {
                bf[nf][0] = *(const bf16x8*)(bb + B0 + (nf << 10) + c0);
                bf[nf][1] = *(const bf16x8*)(bb + B0 + (nf << 10) + (c0 ^ 32));
            }
#pragma unroll
            for (int mf = 0; mf < 8; ++mf) {
                if ((wm << 7) + (mf << 4) < vrows) {
                    bf16x8 a0 = *(const bf16x8*)(ab + A0 + (mf << 10) + c0);
                    bf16x8 a1 = *(const bf16x8*)(ab + A0 + (mf << 10) + (c0 ^ 32));
#pragma unroll
                    for (int nf = 0; nf < 4; ++nf) {
                        acc[mf][nf] = __builtin_amdgcn_mfma_f32_16x16x32_bf16(a0, bf[nf][0], acc[mf][nf], 0, 0, 0);
                        acc[mf][nf] = __builtin_amdgcn_mfma_f32_16x16x32_bf16(a1, bf[nf][1], acc[mf][nf], 0, 0, 0);
                    }
                }
            }
        }
        __builtin_amdgcn_sched_barrier(0);
        __builtin_amdgcn_s_barrier();
    }
#undef STAGE

    // epilogue: tanh-reduce over this block's 64 cols per wave, atomic per row
    float cbv[4], vvv[4];
    int gcs[4];
#pragma unroll
    for (int nf = 0; nf < 4; ++nf) {
        int gc = n0 + (wn << 6) + (nf << 4) + l16;
        gcs[nf] = gc; cbv[nf] = cb[gc]; vvv[nf] = vv[gc];
    }
#pragma unroll
    for (int mf = 0; mf < 8; ++mf) {
        int rloc = (wm << 7) + (mf << 4);
        if (rloc < vrows) {
#pragma unroll
            for (int r = 0; r < 4; ++r) {
                int gr = m0 + rloc + (lq << 2) + r;
                const float* rbp = rb + (size_t)(gr / rpb) * 1024;
                float s = 0.f;
#pragma unroll
                for (int nf = 0; nf < 4; ++nf) {
                    float x = acc[mf][nf][r] + rbp[gcs[nf]] + cbv[nf];
                    s += ftanh(x) * vvv[nf];
                }
#pragma unroll
                for (int m2 = 1; m2 < 16; m2 <<= 1) s += __shfl_xor(s, m2, 64);
                if (l16 == 0) atomicAdd(&out[gr], s);
            }
        }
    }
}

// ---------------------------------------------------------------------------
// m97-style bf16 MFMA GEMM: 128x128 tile, BK=32, double-buffered LDS,
// global_load_lds staging (both operands bf16, Bt is N x K row-major).
// EPI 1: tanh-reduce.  EPI 2: atomicAdd accumulate (split-K).
// ---------------------------------------------------------------------------
template<int EPI>
__device__ __forceinline__ void mgemm(
    const unsigned short* __restrict__ A, const unsigned short* __restrict__ Bt,
    float* __restrict__ out, const float* __restrict__ rb,
    const float* __restrict__ cb1, const float* __restrict__ cb2,
    const float* __restrict__ vvec,
    int m0, int n0, int kb, int ke, int ldk, int ldc, int rpb)
{
    __shared__ unsigned short As[2][4096];
    __shared__ unsigned short Bs[2][4096];
    const int t = threadIdx.x, lane = t & 63, wv = t >> 6;
    const int l16 = lane & 15, lq = lane >> 4;
    const int wm = wv >> 1, wn = wv & 1;

    const int srow = lane >> 2, scol = (lane & 3) << 3;
    const unsigned short* gA0 = A + (size_t)(m0 + (wv << 4) + srow) * ldk + kb + scol;
    const unsigned short* gA1 = gA0 + (size_t)64 * ldk;
    const unsigned short* gB0 = Bt + (size_t)(n0 + (wv << 4) + srow) * ldk + kb + scol;
    const unsigned short* gB1 = gB0 + (size_t)64 * ldk;
    unsigned short* lA0 = &As[0][wv << 9];
    unsigned short* lA1 = &As[0][(wv + 4) << 9];
    unsigned short* lB0 = &Bs[0][wv << 9];
    unsigned short* lB1 = &Bs[0][(wv + 4) << 9];

    f32x4 acc[4][4];
#pragma unroll
    for (int i = 0; i < 4; ++i)
#pragma unroll
        for (int j = 0; j < 4; ++j) acc[i][j] = (f32x4){0.f, 0.f, 0.f, 0.f};

    const int NS = (ke - kb) >> 5;
    gload16(gA0, lA0); gload16(gA1, lA1);
    gload16(gB0, lB0); gload16(gB1, lB1);

    for (int s = 0; s < NS; ++s) {
        __syncthreads();
        if (s + 1 < NS) {
            const int nb = (s + 1) & 1, ko = (s + 1) << 5;
            gload16(gA0 + ko, lA0 + (nb << 12)); gload16(gA1 + ko, lA1 + (nb << 12));
            gload16(gB0 + ko, lB0 + (nb << 12)); gload16(gB1 + ko, lB1 + (nb << 12));
        }
        const unsigned short* ab = As[s & 1];
        const unsigned short* bb = Bs[s & 1];
        bf16x8 af[4], bfv[4];
#pragma unroll
        for (int i = 0; i < 4; ++i)
            af[i] = *(const bf16x8*)(ab + (((wm << 6) + (i << 4) + l16) << 5) + (lq << 3));
#pragma unroll
        for (int i = 0; i < 4; ++i)
            bfv[i] = *(const bf16x8*)(bb + (((wn << 6) + (i << 4) + l16) << 5) + (lq << 3));
#pragma unroll
        for (int mf = 0; mf < 4; ++mf)
#pragma unroll
            for (int nf = 0; nf < 4; ++nf)
                acc[mf][nf] = __builtin_amdgcn_mfma_f32_16x16x32_bf16(af[mf], bfv[nf], acc[mf][nf], 0, 0, 0);
    }

    if (EPI == 1) {
#pragma unroll
        for (int mf = 0; mf < 4; ++mf) {
#pragma unroll
            for (int r = 0; r < 4; ++r) {
                int gr = m0 + (wm << 6) + (mf << 4) + (lq << 2) + r;
                const float* rbp = rb + (size_t)(gr / rpb) * 1024;
                float s = 0.0f;
#pragma unroll
                for (int nf = 0; nf < 4; ++nf) {
                    int gc = n0 + (wn << 6) + (nf << 4) + l16;
                    float xv = acc[mf][nf][r] + rbp[gc] + cb1[gc];
                    if (cb2) xv += cb2[gc];
                    s += ftanh(xv) * vvec[gc];
                }
#pragma unroll
                for (int msk = 1; msk < 16; msk <<= 1) s += __shfl_xor(s, msk, 64);
                if (l16 == 0) atomicAdd(&out[gr], s);
            }
        }
    } else {
#pragma unroll
        for (int mf = 0; mf < 4; ++mf) {
            int gr0 = m0 + (wm << 6) + (mf << 4) + (lq << 2);
#pragma unroll
            for (int nf = 0; nf < 4; ++nf) {
                int gc = n0 + (wn << 6) + (nf << 4) + l16;
#pragma unroll
                for (int r = 0; r < 4; ++r)
                    atomicAdd(&out[(size_t)(gr0 + r) * ldc + gc], acc[mf][nf][r]);
            }
        }
    }
}

// gene logits body: A = hnew bf16 (gload_lds), B = W_out f32 KxN (reg-stage
// cvt), full K=1024, plain store with fused bias.
__device__ __forceinline__ void gene_body(
    const unsigned short* __restrict__ hnb, const float* __restrict__ Wout,
    const float* __restrict__ b_out, float* __restrict__ out, int n0)
{
    __shared__ unsigned short As[2][4096];
    __shared__ unsigned short Bs[2][4096];
    const int t = threadIdx.x, lane = t & 63, wv = t >> 6;
    const int l16 = lane & 15, lq = lane >> 4;
    const int wm = wv >> 1, wn = wv & 1;

    const int srow = lane >> 2, scol = (lane & 3) << 3;
    const unsigned short* gA0 = hnb + (size_t)((wv << 4) + srow) * 1024 + scol;
    const unsigned short* gA1 = gA0 + (size_t)64 * 1024;
    unsigned short* lA0 = &As[0][wv << 9];
    unsigned short* lA1 = &As[0][(wv + 4) << 9];

    const int bn = t & 127, kh = t >> 7;
    const bool ok = (n0 + bn) < 40000;
    const float* gB = Wout + (size_t)(kh * 16) * 40000 + (n0 + bn);

    f32x4 acc[4][4];
#pragma unroll
    for (int i = 0; i < 4; ++i)
#pragma unroll
        for (int j = 0; j < 4; ++j) acc[i][j] = (f32x4){0.f, 0.f, 0.f, 0.f};

    auto stageB = [&](int buf, int ko) {
        const float* src = gB + (size_t)ko * 40000;
        float f[16];
#pragma unroll
        for (int j = 0; j < 16; ++j) f[j] = ok ? src[(size_t)j * 40000] : 0.0f;
        u32x4* d = (u32x4*)&Bs[buf][bn * 32 + kh * 16];
        d[0] = (u32x4){pack2(f[0],f[1]), pack2(f[2],f[3]), pack2(f[4],f[5]), pack2(f[6],f[7])};
        d[1] = (u32x4){pack2(f[8],f[9]), pack2(f[10],f[11]), pack2(f[12],f[13]), pack2(f[14],f[15])};
    };

    gload16(gA0, lA0); gload16(gA1, lA1); stageB(0, 0);
    for (int s = 0; s < 32; ++s) {
        __syncthreads();
        if (s + 1 < 32) {
            const int nb = (s + 1) & 1, ko = (s + 1) << 5;
            gload16(gA0 + ko, lA0 + (nb << 12)); gload16(gA1 + ko, lA1 + (nb << 12));
            stageB(nb, ko);
        }
        const unsigned short* ab = As[s & 1];
        const unsigned short* bb = Bs[s & 1];
        bf16x8 af[4], bfv[4];
#pragma unroll
        for (int i = 0; i < 4; ++i)
            af[i] = *(const bf16x8*)(ab + (((wm << 6) + (i << 4) + l16) << 5) + (lq << 3));
#pragma unroll
        for (int i = 0; i < 4; ++i)
            bfv[i] = *(const bf16x8*)(bb + (((wn << 6) + (i << 4) + l16) << 5) + (lq << 3));
#pragma unroll
        for (int mf = 0; mf < 4; ++mf)
#pragma unroll
            for (int nf = 0; nf < 4; ++nf)
                acc[mf][nf] = __builtin_amdgcn_mfma_f32_16x16x32_bf16(af[mf], bfv[nf], acc[mf][nf], 0, 0, 0);
    }
#pragma unroll
    for (int mf = 0; mf < 4; ++mf) {
        int gr0 = (wm << 6) + (mf << 4) + (lq << 2);
#pragma unroll
        for (int nf = 0; nf < 4; ++nf) {
            int gc = n0 + (wn << 6) + (nf << 4) + l16;
            if (gc < 40000) {
                float bo = b_out[gc];
#pragma unroll
                for (int r = 0; r < 4; ++r)
                    out[(size_t)(gr0 + r) * 40000 + gc] = acc[mf][nf][r] + bo;
            }
        }
    }
}

// ------------------------------ GEMM wrappers ------------------------------
__global__ __launch_bounds__(256) void k_stac3(
    const unsigned short* se, const unsigned short* ae, const unsigned short* WmscT,
    const float* tagrow, const float* qsc, const float* bq_sc, const float* v_sc,
    float* stlg, float* aclg) {
    if (blockIdx.z == 0)
        mgemm<1>(se, WmscT, stlg, qsc, bq_sc, nullptr, v_sc, blockIdx.y * 128, blockIdx.x * 128, 0, 1024, 1024, 0, 10);
    else
        mgemm<1>(ae, WmscT, aclg, qsc, bq_sc, tagrow, v_sc, blockIdx.y * 128, blockIdx.x * 128, 0, 1024, 1024, 0, 10);
}

__global__ __launch_bounds__(256) void k_qh4(
    const unsigned short* q0, const unsigned short* W0, const unsigned short* W1,
    const unsigned short* W2, float* o0, float* o1, float* o2) {
    const unsigned short* W = W0; float* o = o0;
    if (blockIdx.z == 1) { W = W1; o = o1; }
    if (blockIdx.z == 2) { W = W2; o = o2; }
    int kb = blockIdx.y << 8;
    mgemm<2>(q0, W, o, nullptr, nullptr, nullptr, nullptr, 0, blockIdx.x * 128, kb, kb + 256, 1024, 1024, 1);
}

__global__ __launch_bounds__(256) void k_gigh2(
    const unsigned short* xb, const unsigned short* q0,
    const unsigned short* Wih, const unsigned short* Whh, float* gi, float* gh) {
    if (blockIdx.z == 0) {
        int kb = blockIdx.y << 9;
        mgemm<2>(xb, Wih, gi, nullptr, nullptr, nullptr, nullptr, 0, blockIdx.x * 128, kb, kb + 512, 4096, 3072, 1);
    } else {
        if (blockIdx.y >= 2) return;
        int kb = blockIdx.y << 9;
        mgemm<2>(q0, Whh, gh, nullptr, nullptr, nullptr, nullptr, 0, blockIdx.x * 128, kb, kb + 512, 1024, 3072, 1);
    }
}

// qsc (16 blocks, split-K 2) + gene logits (313 blocks) in one launch
__global__ __launch_bounds__(256) void k_qsc_gene(
    const unsigned short* hnb, const unsigned short* WqscT, float* qsc,
    const float* Wout, const float* b_out, float* out) {
    int id = blockIdx.x;
    if (id < 16) {
        int x = id & 7, kb = (id >> 3) << 9;
        mgemm<2>(hnb, WqscT, qsc, nullptr, nullptr, nullptr, nullptr, 0, x * 128, kb, kb + 512, 1024, 1024, 1);
    } else {
        gene_body(hnb, Wout, b_out, out, (id - 16) << 7);
    }
}

// --------------------------- prep kernels -----------------------------------
struct CvtArgs { const float* s[6]; unsigned short* d[6]; int pre[7]; };
__global__ __launch_bounds__(256) void k_cvt_all(CvtArgs a) {
    int total = a.pre[6];
    for (int i = blockIdx.x * 256 + threadIdx.x; i < total; i += gridDim.x * 256) {
        int seg = 0;
        while (i >= a.pre[seg + 1]) ++seg;
        int loc = i - a.pre[seg];
        const f32x4* s4 = (const f32x4*)a.s[seg] + (size_t)loc * 2;
        f32x4 q0 = s4[0], q1 = s4[1];
        ((u32x4*)a.d[seg])[loc] =
            (u32x4){pack2(q0[0],q0[1]), pack2(q0[2],q0[3]), pack2(q1[0],q1[1]), pack2(q1[2],q1[3])};
    }
}

struct TrArgs { const float* s[8]; unsigned short* d[8]; };
__global__ __launch_bounds__(256) void k_trcvt(TrArgs a) {
    __shared__ float tile[64][65];
    const float* in = a.s[blockIdx.z];
    unsigned short* ot = a.d[blockIdx.z];
    int k0 = blockIdx.y << 6, n0 = blockIdx.x << 6;
    int tr = threadIdx.x >> 6, tc = threadIdx.x & 63;
#pragma unroll
    for (int i = 0; i < 16; ++i) {
        int r = (i << 2) + tr;
        tile[r][tc] = in[(size_t)(k0 + r) * 1024 + n0 + tc];
    }
    __syncthreads();
#pragma unroll
    for (int i = 0; i < 16; ++i) {
        int r = (i << 2) + tr;
        ot[(size_t)(n0 + r) * 1024 + k0 + tc] = (unsigned short)rne_bf16(tile[tc][r]);
    }
}

// --------------------------- non-GEMM kernels ------------------------------
__device__ __forceinline__ void softmax10(const float* src, float* dst) {
    float m = src[0];
    for (int i = 1; i < 10; ++i) m = fmaxf(m, src[i]);
    float z = 0.f, e[10];
    for (int i = 0; i < 10; ++i) { e[i] = expf(src[i] - m); z += e[i]; }
    float iz = 1.0f / z;
    for (int i = 0; i < 10; ++i) dst[i] = e[i] * iz;
}

// hist softmax + c_his, inp copy, state/action softmax + contexts -> x (bf16)
__global__ __launch_bounds__(256) void k_ctx(
    const float* __restrict__ scores, const int* __restrict__ lens,
    const unsigned short* __restrict__ hs,
    const float* __restrict__ inp, const float* __restrict__ st_sc, const float* __restrict__ ac_sc,
    const unsigned short* __restrict__ se, const unsigned short* __restrict__ ae,
    unsigned short* __restrict__ xb) {
    int b = blockIdx.x, t = threadIdx.x;
    __shared__ float w[256];
    __shared__ float red[256];
    __shared__ float sw[10], aw[10];
    int len = lens[b];
    float s = scores[b * 256 + t];
    bool valid = t < len;
    red[t] = valid ? s : -3.0e38f;
    __syncthreads();
    for (int st = 128; st > 0; st >>= 1) { if (t < st) red[t] = fmaxf(red[t], red[t + st]); __syncthreads(); }
    float m = red[0];
    __syncthreads();
    float e = valid ? expf(s - m) : 0.0f;
    red[t] = e;
    __syncthreads();
    for (int st = 128; st > 0; st >>= 1) { if (t < st) red[t] += red[t + st]; __syncthreads(); }
    float Z = red[0];
    __syncthreads();
    w[t] = e / Z;
    if (t == 0) softmax10(st_sc + b * 10, sw);
    if (t == 64) softmax10(ac_sc + b * 10, aw);
    f32x4 iv = ((const f32x4*)(inp + (size_t)b * 1024))[t];
    *((u32x2*)(xb + (size_t)b * 4096) + t) = (u32x2){pack2(iv[0], iv[1]), pack2(iv[2], iv[3])};
    __syncthreads();
    float a0 = 0.f, a1 = 0.f, a2 = 0.f, a3 = 0.f;
    for (int l = 0; l < 256; ++l) {
        float wl = w[l];
        if (wl == 0.0f) continue;
        u32x2 u = *((const u32x2*)(hs + ((size_t)b * 256 + l) * 1024) + t);
        a0 += wl * bf2f(u[0]); a1 += wl * bf2f(u[0] >> 16);
        a2 += wl * bf2f(u[1]); a3 += wl * bf2f(u[1] >> 16);
    }
    *((u32x2*)(xb + (size_t)b * 4096 + 1024) + t) = (u32x2){pack2(a0, a1), pack2(a2, a3)};
    float cs0=0,cs1=0,cs2=0,cs3=0, ca0=0,ca1=0,ca2=0,ca3=0;
#pragma unroll
    for (int q = 0; q < 10; ++q) {
        u32x2 us = *((const u32x2*)(se + ((size_t)b * 10 + q) * 1024) + t);
        u32x2 ua = *((const u32x2*)(ae + ((size_t)b * 10 + q) * 1024) + t);
        float ws = sw[q], wa = aw[q];
        cs0 += ws * bf2f(us[0]); cs1 += ws * bf2f(us[0] >> 16);
        cs2 += ws * bf2f(us[1]); cs3 += ws * bf2f(us[1] >> 16);
        ca0 += wa * bf2f(ua[0]); ca1 += wa * bf2f(ua[0] >> 16);
        ca2 += wa * bf2f(ua[1]); ca3 += wa * bf2f(ua[1] >> 16);
    }
    *((u32x2*)(xb + (size_t)b * 4096 + 2048) + t) = (u32x2){pack2(cs0, cs1), pack2(cs2, cs3)};
    *((u32x2*)(xb + (size_t)b * 4096 + 3072) + t) = (u32x2){pack2(ca0, ca1), pack2(ca2, ca3)};
}

// GRU elementwise + hs_logits (h_new . hs_vectors) fused; one block per b
__global__ __launch_bounds__(1024) void k_gruhsl(
    const float* __restrict__ gi, const float* __restrict__ gh,
    const float* __restrict__ b_ih, const float* __restrict__ b_hh,
    const float* __restrict__ h0, float* __restrict__ hnew,
    unsigned short* __restrict__ hnb,
    const unsigned short* __restrict__ hs, float* __restrict__ hsl) {
    int b = blockIdx.x, j = threadIdx.x;
    size_t i = (size_t)b * 1024 + j;
    const float* gib = gi + (size_t)b * 3072;
    const float* ghb = gh + (size_t)b * 3072;
    float r = sigm(gib[j] + b_ih[j] + ghb[j] + b_hh[j]);
    float z = sigm(gib[1024 + j] + b_ih[1024 + j] + ghb[1024 + j] + b_hh[1024 + j]);
    float hn = ghb[2048 + j] + b_hh[2048 + j];
    float n = tanhf(gib[2048 + j] + b_ih[2048 + j] + r * hn);
    float h = (1.0f - z) * n + z * h0[i];
    hnew[i] = h;
    hnb[i] = (unsigned short)rne_bf16(h);
    __shared__ float hsm[1024];
    hsm[j] = h;
    __syncthreads();
    int wave = j >> 6, lane = j & 63;
    float hr[16];
#pragma unroll
    for (int k = 0; k < 16; ++k) hr[k] = hsm[lane * 16 + k];
    for (int l = wave; l < 256; l += 16) {
        const u32x4* row = (const u32x4*)(hs + ((size_t)b * 256 + l) * 1024);
        u32x4 u0 = row[lane * 2], u1 = row[lane * 2 + 1];
        float s = hr[0]*bf2f(u0[0]) + hr[1]*bf2f(u0[0]>>16) + hr[2]*bf2f(u0[1]) + hr[3]*bf2f(u0[1]>>16)
                + hr[4]*bf2f(u0[2]) + hr[5]*bf2f(u0[2]>>16) + hr[6]*bf2f(u0[3]) + hr[7]*bf2f(u0[3]>>16)
                + hr[8]*bf2f(u1[0]) + hr[9]*bf2f(u1[0]>>16) + hr[10]*bf2f(u1[1]) + hr[11]*bf2f(u1[1]>>16)
                + hr[12]*bf2f(u1[2]) + hr[13]*bf2f(u1[2]>>16) + hr[14]*bf2f(u1[3]) + hr[15]*bf2f(u1[3]>>16);
#pragma unroll
        for (int msk = 1; msk < 64; msk <<= 1) s += __shfl_xor(s, msk, 64);
        if (lane == 0) hsl[b * 256 + l] = s;
    }
}

// softmax stats over concat + copy_p scatter; one block per b
__global__ __launch_bounds__(256) void k_smsc(
    const float* __restrict__ gene, const float* __restrict__ hsl,
    const float* __restrict__ stl, const float* __restrict__ acl,
    const int* __restrict__ hwi,
    float* __restrict__ mbuf, float* __restrict__ zbuf, float* __restrict__ copyp) {
    int b = blockIdx.x, t = threadIdx.x;
    __shared__ float red[256];
    const f32x4* g4 = (const f32x4*)(gene + (size_t)b * 40000);
    float mx = -3.0e38f;
    for (int i = t; i < 10000; i += 256) {
        f32x4 q = g4[i];
        mx = fmaxf(mx, fmaxf(fmaxf(q[0], q[1]), fmaxf(q[2], q[3])));
    }
    float hv = hsl[b * 256 + t];
    mx = fmaxf(mx, hv);
    if (t < 10) mx = fmaxf(mx, fmaxf(stl[b * 10 + t], acl[b * 10 + t]));
    red[t] = mx; __syncthreads();
    for (int s = 128; s > 0; s >>= 1) { if (t < s) red[t] = fmaxf(red[t], red[t + s]); __syncthreads(); }
    float m = red[0];
    __syncthreads();
    float sum = 0.f;
    for (int i = t; i < 10000; i += 256) {
        f32x4 q = g4[i];
        sum += expf(q[0]-m) + expf(q[1]-m) + expf(q[2]-m) + expf(q[3]-m);
    }
    sum += expf(hv - m);
    if (t < 10) sum += expf(stl[b * 10 + t] - m) + expf(acl[b * 10 + t] - m);
    red[t] = sum; __syncthreads();
    for (int s = 128; s > 0; s >>= 1) { if (t < s) red[t] += red[t + s]; __syncthreads(); }
    float Z = red[0];
    if (t == 0) { mbuf[b] = m; zbuf[b] = Z; }
    float wv = expf(hv - m) / Z;
    atomicAdd(copyp + (size_t)b * 40000 + hwi[b * 256 + t], wv);
}

__global__ __launch_bounds__(256) void k_final(
    float* __restrict__ gene_out, const float* __restrict__ copyp,
    const float* __restrict__ sprob, const float* __restrict__ aprob,
    const float* __restrict__ stl, const float* __restrict__ acl,
    const float* __restrict__ mbuf, const float* __restrict__ zbuf) {
    int b = blockIdx.y, t = threadIdx.x;
    __shared__ float sw[10], aw[10];
    float m = mbuf[b], iz = 1.0f / zbuf[b];
    if (t < 10) sw[t] = expf(stl[b * 10 + t] - m) * iz;
    if (t >= 64 && t < 74) aw[t - 64] = expf(acl[b * 10 + (t - 64)] - m) * iz;
    __syncthreads();
    int v4 = blockIdx.x * 256 + t;
    if (v4 < 10000) {
        size_t base = (size_t)b * 10000 + v4;
        f32x4 g = ((const f32x4*)gene_out)[base];
        f32x4 c = ((const f32x4*)copyp)[base];
        f32x4 acc;
#pragma unroll
        for (int j = 0; j < 4; ++j) acc[j] = expf(g[j] - m) * iz + c[j];
#pragma unroll
        for (int s = 0; s < 10; ++s) {
            f32x4 pv = ((const f32x4*)sprob)[((size_t)b * 10 + s) * 10000 + v4];
            f32x4 av = ((const f32x4*)aprob)[((size_t)b * 10 + s) * 10000 + v4];
            float ws = sw[s], wa = aw[s];
#pragma unroll
            for (int j = 0; j < 4; ++j) acc[j] += ws * pv[j] + wa * av[j];
        }
        f32x4 r;
#pragma unroll
        for (int j = 0; j < 4; ++j) r[j] = logf(acc[j]);
        ((f32x4*)gene_out)[base] = r;
    }
}

// ------------------------------- launcher ----------------------------------
// float ws region (floats)
#define OFF_QH_H  0
#define OFF_QH_S  131072
#define OFF_QH_A  262144
#define OFF_QSC   393216
#define OFF_GI    524288
#define OFF_GH    917504
#define OFF_HSC   1310720
#define OFF_STSC  1343488
#define OFF_ACSC  1344768
#define OFF_STLG  1346048
#define OFF_ACLG  1347328
#define ZERO_FLOATS 1348608
#define OFF_HSL   1348608
#define OFF_M     1381376
#define OFF_Z     1381504
#define OFF_COPY  1381632
#define FLOAT_TOTAL 6501632
// short region (shorts, offset from short base)
#define SO_HS     0
#define SO_SE     33554432
#define SO_AE     34865152
#define SO_Q0     36175872
#define SO_X      36306944
#define SO_HNB    36831232
#define SO_WQHT   36962304
#define SO_WQST   38010880
#define SO_WQAT   39059456
#define SO_WQSCT  40108032
#define SO_WMHT   41156608
#define SO_WMST   42205184
#define SO_WMAT   43253760
#define SO_WMSCT  44302336
#define SO_WIH    45350912
#define SO_WHH    57933824

extern "C" void kernel_launch(void* const* d_in, const int* in_sizes, int n_in,
                              void* d_out, int out_size, void* d_ws, size_t ws_size,
                              hipStream_t stream) {
    const float* inp     = (const float*)d_in[0];
    const float* hidden  = (const float*)d_in[1];
    const float* hs      = (const float*)d_in[2];
    const float* sprob   = (const float*)d_in[3];
    const float* se      = (const float*)d_in[4];
    const float* aprob   = (const float*)d_in[5];
    const float* ae      = (const float*)d_in[6];
    const int*   lens    = (const int*)d_in[7];
    const int*   hwi     = (const int*)d_in[8];
    const float* Wq_hist = (const float*)d_in[9];
    const float* bq_hist = (const float*)d_in[10];
    const float* Wm_hist = (const float*)d_in[11];
    const float* v_hist  = (const float*)d_in[12];
    const float* Wq_s    = (const float*)d_in[13];
    const float* bq_s    = (const float*)d_in[14];
    const float* Wm_s    = (const float*)d_in[15];
    const float* v_s     = (const float*)d_in[16];
    const float* Wq_a    = (const float*)d_in[17];
    const float* bq_a    = (const float*)d_in[18];
    const float* Wm_a    = (const float*)d_in[19];
    const float* v_a     = (const float*)d_in[20];
    const float* Wq_sc   = (const float*)d_in[21];
    const float* bq_sc   = (const float*)d_in[22];
    const float* Wm_sc   = (const float*)d_in[23];
    const float* v_sc    = (const float*)d_in[24];
    const float* W_ih    = (const float*)d_in[25];
    const float* W_hh    = (const float*)d_in[26];
    const float* b_ih    = (const float*)d_in[27];
    const float* b_hh    = (const float*)d_in[28];
    const float* W_out   = (const float*)d_in[29];
    const float* b_out   = (const float*)d_in[30];

    float* out  = (float*)d_out;
    float* w    = (float*)d_ws;
    float* hnew = out + BV;
    unsigned short* sb = (unsigned short*)(w + FLOAT_TOTAL);

    float* qh_h = w + OFF_QH_H;  float* qh_s = w + OFF_QH_S;  float* qh_a = w + OFF_QH_A;
    float* qsc  = w + OFF_QSC;   float* gi   = w + OFF_GI;    float* gh   = w + OFF_GH;
    float* hsc  = w + OFF_HSC;   float* stsc = w + OFF_STSC;  float* acsc = w + OFF_ACSC;
    float* stlg = w + OFF_STLG;  float* aclg = w + OFF_ACLG;
    float* hsl  = w + OFF_HSL;   float* mbuf = w + OFF_M;     float* zbuf = w + OFF_Z;
    float* copyp = w + OFF_COPY;

    unsigned short* hs_bf = sb + SO_HS;   unsigned short* se_bf = sb + SO_SE;
    unsigned short* ae_bf = sb + SO_AE;   unsigned short* q0_bf = sb + SO_Q0;
    unsigned short* x_bf  = sb + SO_X;    unsigned short* hnb   = sb + SO_HNB;
    unsigned short* WqhT  = sb + SO_WQHT; unsigned short* WqsT  = sb + SO_WQST;
    unsigned short* WqaT  = sb + SO_WQAT; unsigned short* WqscT = sb + SO_WQSCT;
    unsigned short* WmhT  = sb + SO_WMHT; unsigned short* WmsT  = sb + SO_WMST;
    unsigned short* WmaT  = sb + SO_WMAT; unsigned short* WmscT = sb + SO_WMSCT;
    unsigned short* WihB  = sb + SO_WIH;  unsigned short* WhhB  = sb + SO_WHH;

    dim3 blk(256);

    hipMemsetAsync(w, 0, (size_t)ZERO_FLOATS * 4, stream);
    hipMemsetAsync(copyp, 0, (size_t)BV * 4, stream);

    // bf16 conversions (one kernel)
    CvtArgs ca;
    ca.s[0]=hs; ca.s[1]=se; ca.s[2]=ae; ca.s[3]=hidden; ca.s[4]=W_ih; ca.s[5]=W_hh;
    ca.d[0]=hs_bf; ca.d[1]=se_bf; ca.d[2]=ae_bf; ca.d[3]=q0_bf; ca.d[4]=WihB; ca.d[5]=WhhB;
    ca.pre[0]=0; ca.pre[1]=4194304; ca.pre[2]=4358144; ca.pre[3]=4521984;
    ca.pre[4]=4538368; ca.pre[5]=6111232; ca.pre[6]=6504448;
    k_cvt_all<<<dim3(4096), blk, 0, stream>>>(ca);

    TrArgs ta;
    ta.s[0]=Wq_hist; ta.s[1]=Wq_s; ta.s[2]=Wq_a; ta.s[3]=Wq_sc;
    ta.s[4]=Wm_hist; ta.s[5]=Wm_s; ta.s[6]=Wm_a; ta.s[7]=Wm_sc;
    ta.d[0]=WqhT; ta.d[1]=WqsT; ta.d[2]=WqaT; ta.d[3]=WqscT;
    ta.d[4]=WmhT; ta.d[5]=WmsT; ta.d[6]=WmaT; ta.d[7]=WmscT;
    k_trcvt<<<dim3(16, 16, 8), blk, 0, stream>>>(ta);

    // q-projections (split-K atomic, bias folded into consumers)
    k_qh4<<<dim3(8, 4, 3), blk, 0, stream>>>(q0_bf, WqhT, WqsT, WqaT, qh_h, qh_s, qh_a);

    // big hist MLP + state/action score MLPs: 256^2 counted-vmcnt pipeline
    BigArgs ba;
    ba.hs = hs_bf; ba.WmhT = WmhT; ba.se = se_bf; ba.ae = ae_bf;
    ba.WmsT = WmsT; ba.WmaT = WmaT; ba.lens = lens;
    ba.qh_h = qh_h; ba.bq_h = bq_hist; ba.v_h = v_hist;
    ba.qh_s = qh_s; ba.bq_s = bq_s; ba.v_s = v_s;
    ba.qh_a = qh_a; ba.bq_a = bq_a; ba.v_a = v_a;
    ba.hsc = hsc; ba.stsc = stsc; ba.acsc = acsc;
    k_big<<<dim3(552), dim3(512), 0, stream>>>(ba);

    // contexts -> x (bf16)
    k_ctx<<<dim3(128), blk, 0, stream>>>(hsc, lens, hs_bf, inp, stsc, acsc, se_bf, ae_bf, x_bf);
    // GRU gates
    k_gigh2<<<dim3(24, 8, 2), blk, 0, stream>>>(x_bf, q0_bf, WihB, WhhB, gi, gh);
    // GRU elementwise + hs logits
    k_gruhsl<<<dim3(128), dim3(1024), 0, stream>>>(gi, gh, b_ih, b_hh, hidden, hnew, hnb, hs_bf, hsl);
    // copy-scorer query + gene logits (bias fused into store)
    k_qsc_gene<<<dim3(329), blk, 0, stream>>>(hnb, WqscT, qsc, W_out, b_out, out);
    // st / ac logits
    k_stac3<<<dim3(8, 10, 2), blk, 0, stream>>>(se_bf, ae_bf, WmscT, Wm_sc + (size_t)1024 * 1024,
                                                qsc, bq_sc, v_sc, stlg, aclg);
    // softmax stats + scatter, then fused final
    k_smsc<<<dim3(128), blk, 0, stream>>>(out, hsl, stlg, aclg, hwi, mbuf, zbuf, copyp);
    k_final<<<dim3(40, 128), blk, 0, stream>>>(out, copyp, sprob, aprob, stlg, aclg, mbuf, zbuf);

    (void)in_sizes; (void)n_in; (void)out_size; (void)ws_size;
}

// Round 5
// 553.105 us; speedup vs baseline: 1.9128x; 1.0402x over previous
//
#include <hip/hip_runtime.h>
#include <stdint.h>

typedef __attribute__((ext_vector_type(4))) float f32x4;
typedef __attribute__((ext_vector_type(2))) unsigned int u32x2;
typedef __attribute__((ext_vector_type(4))) unsigned int u32x4;
typedef __attribute__((ext_vector_type(8))) short bf16x8;

#define BV (128*40000)

__device__ __forceinline__ unsigned rne_bf16(float f) {
    unsigned x = __float_as_uint(f);
    return ((x + 0x7FFFu + ((x >> 16) & 1u)) >> 16) & 0xFFFFu;
}
__device__ __forceinline__ unsigned pack2(float a, float b) {
    return rne_bf16(a) | (rne_bf16(b) << 16);
}
__device__ __forceinline__ float bf2f(unsigned u) {
    return __uint_as_float((u & 0xFFFFu) << 16);
}
__device__ __forceinline__ float sigm(float x) { return 1.0f / (1.0f + expf(-x)); }
__device__ __forceinline__ float ftanh(float x) {
    float e = __expf(2.0f * x);
    return 1.0f - 2.0f / (e + 1.0f);
}

__device__ __forceinline__ void gload16(const void* g, void* l) {
    __builtin_amdgcn_global_load_lds(
        (const __attribute__((address_space(1))) unsigned*)g,
        (__attribute__((address_space(3))) unsigned*)l, 16, 0, 0);
}

// ---------------------------------------------------------------------------
// Persistent 256x256-tile bf16 MFMA GEMM, counted-vmcnt double-buffered
// pipeline, dynamic tile queue (atomic counter). 256 blocks = 1/CU.
// 512 threads = 8 waves (2M x 4N), wave tile 128x64, BK=64, LDS 128 KiB.
// XOR chunk swizzle (cc ^= row&7) on global source AND ds_read.
// Tiles: 0..39 = state/action score MLPs, 40..551 = hist MLP (mask-skipped).
// ---------------------------------------------------------------------------
struct BigArgs {
    const unsigned short *hs, *WmhT, *se, *ae, *WmsT, *WmaT;
    const int* lens;
    const float *qh_h, *bq_h, *v_h;
    const float *qh_s, *bq_s, *v_s;
    const float *qh_a, *bq_a, *v_a;
    float *hsc, *stsc, *acsc;
};

__global__ __launch_bounds__(512, 1) void k_big(BigArgs a, int* __restrict__ ctr) {
    __shared__ unsigned short As[2][16384];
    __shared__ unsigned short Bs[2][16384];
    __shared__ int sTile;

    const int t = threadIdx.x, lane = t & 63, wv = t >> 6;
    const int l16 = lane & 15, lq = lane >> 4;
    const int wm = wv >> 2, wn = wv & 3;

    // staging: thread t covers chunk (row = srowL(+h*128+r*64), cc = t&7),
    // global source column pre-swizzled: gcc = (t&7) ^ (srowL&7)
    const int srowL = t >> 3;
    const int gccA = ((t & 7) ^ (srowL & 7)) << 3;
    // ds_read swizzle constants
    const int sw = l16 & 7;
    const int c0 = ((lq ^ sw) << 3);          // ks=0 chunk; ks=1 = c0^32
    const int A0 = (wm << 13) + (l16 << 6);
    const int B0 = ((wn >> 1) << 13) + ((((wn & 1) << 6) + l16) << 6);

#define STAGE(kt, d)                                                          \
    {                                                                         \
        const unsigned short* ga_ = gA + (size_t)(kt) * 64;                   \
        const unsigned short* gb_ = gB + (size_t)(kt) * 64;                   \
        _Pragma("unroll")                                                     \
        for (int h_ = 0; h_ < 2; ++h_) {                                      \
            _Pragma("unroll")                                                 \
            for (int r_ = 0; r_ < 2; ++r_) {                                  \
                size_t go_ = (size_t)(h_ * 128 + r_ * 64) * 1024;             \
                int lo_ = h_ * 8192 + r_ * 4096 + (wv << 9);                  \
                gload16(ga_ + go_, &As[d][lo_]);                              \
                gload16(gb_ + go_, &Bs[d][lo_]);                              \
            }                                                                 \
        }                                                                     \
    }

    for (;;) {
        __syncthreads();
        if (t == 0) sTile = atomicAdd(ctr, 1);
        __syncthreads();
        const int wg = sTile;
        if (wg >= 552) return;

        const unsigned short *A, *Bt;
        const float *rb, *cb, *vv;
        float* out;
        int m0, n0, vrows, rpb;
        if (wg < 40) {
            int op = wg / 20, r = wg - op * 20;
            int mt = r >> 2, nt = r & 3;
            if (op == 0) { A = a.se; Bt = a.WmsT; rb = a.qh_s; cb = a.bq_s; vv = a.v_s; out = a.stsc; }
            else         { A = a.ae; Bt = a.WmaT; rb = a.qh_a; cb = a.bq_a; vv = a.v_a; out = a.acsc; }
            m0 = mt << 8; n0 = nt << 8; vrows = 256; rpb = 10;
        } else {
            int h = wg - 40;
            int m = h >> 2, n = h & 3;
            A = a.hs; Bt = a.WmhT; rb = a.qh_h; cb = a.bq_h; vv = a.v_h; out = a.hsc;
            m0 = m << 8; n0 = n << 8; vrows = a.lens[m]; rpb = 256;
        }

        const unsigned short* gA = A + (size_t)(m0 + srowL) * 1024 + gccA;
        const unsigned short* gB = Bt + (size_t)(n0 + srowL) * 1024 + gccA;

        f32x4 acc[8][4];
#pragma unroll
        for (int i = 0; i < 8; ++i)
#pragma unroll
            for (int j = 0; j < 4; ++j) acc[i][j] = (f32x4){0.f, 0.f, 0.f, 0.f};

        STAGE(0, 0);
        for (int kt = 0; kt < 16; ++kt) {
            int cur = kt & 1;
            if (kt < 15) {
                STAGE(kt + 1, cur ^ 1);
                asm volatile("s_waitcnt vmcnt(8)" ::: "memory");
            } else {
                asm volatile("s_waitcnt vmcnt(0)" ::: "memory");
            }
            __builtin_amdgcn_s_barrier();
            __builtin_amdgcn_sched_barrier(0);

            const unsigned short* ab = As[cur];
            const unsigned short* bb = Bs[cur];
            if (vrows > (wm << 7)) {
                bf16x8 bf0[4], bf1[4];
#pragma unroll
                for (int nf = 0; nf < 4; ++nf) {
                    bf0[nf] = *(const bf16x8*)(bb + B0 + (nf << 10) + c0);
                    bf1[nf] = *(const bf16x8*)(bb + B0 + (nf << 10) + (c0 ^ 32));
                }
#pragma unroll
                for (int mf = 0; mf < 8; ++mf) {
                    if ((wm << 7) + (mf << 4) < vrows) {
                        bf16x8 a0 = *(const bf16x8*)(ab + A0 + (mf << 10) + c0);
                        bf16x8 a1 = *(const bf16x8*)(ab + A0 + (mf << 10) + (c0 ^ 32));
#pragma unroll
                        for (int nf = 0; nf < 4; ++nf)
                            acc[mf][nf] = __builtin_amdgcn_mfma_f32_16x16x32_bf16(a0, bf0[nf], acc[mf][nf], 0, 0, 0);
#pragma unroll
                        for (int nf = 0; nf < 4; ++nf)
                            acc[mf][nf] = __builtin_amdgcn_mfma_f32_16x16x32_bf16(a1, bf1[nf], acc[mf][nf], 0, 0, 0);
                    }
                }
            }
            __builtin_amdgcn_sched_barrier(0);
            __builtin_amdgcn_s_barrier();
        }

        // epilogue: tanh-reduce over this block's 64 cols per wave, atomic per row
        float cbv[4], vvv[4];
        int gcs[4];
#pragma unroll
        for (int nf = 0; nf < 4; ++nf) {
            int gc = n0 + (wn << 6) + (nf << 4) + l16;
            gcs[nf] = gc; cbv[nf] = cb[gc]; vvv[nf] = vv[gc];
        }
#pragma unroll
        for (int mf = 0; mf < 8; ++mf) {
            int rloc = (wm << 7) + (mf << 4);
            if (rloc < vrows) {
#pragma unroll
                for (int r = 0; r < 4; ++r) {
                    int gr = m0 + rloc + (lq << 2) + r;
                    const float* rbp = rb + (size_t)(gr / rpb) * 1024;
                    float s = 0.f;
#pragma unroll
                    for (int nf = 0; nf < 4; ++nf) {
                        float x = acc[mf][nf][r] + rbp[gcs[nf]] + cbv[nf];
                        s += ftanh(x) * vvv[nf];
                    }
#pragma unroll
                    for (int m2 = 1; m2 < 16; m2 <<= 1) s += __shfl_xor(s, m2, 64);
                    if (l16 == 0) atomicAdd(&out[gr], s);
                }
            }
        }
    }
#undef STAGE
}

// ---------------------------------------------------------------------------
// m97-style bf16 MFMA GEMM: 128x128 tile, BK=32, double-buffered LDS,
// global_load_lds staging (both operands bf16, Bt is N x K row-major).
// EPI 1: tanh-reduce.  EPI 2: atomicAdd accumulate (split-K).
// ---------------------------------------------------------------------------
template<int EPI>
__device__ __forceinline__ void mgemm(
    const unsigned short* __restrict__ A, const unsigned short* __restrict__ Bt,
    float* __restrict__ out, const float* __restrict__ rb,
    const float* __restrict__ cb1, const float* __restrict__ cb2,
    const float* __restrict__ vvec,
    int m0, int n0, int kb, int ke, int ldk, int ldc, int rpb)
{
    __shared__ unsigned short As[2][4096];
    __shared__ unsigned short Bs[2][4096];
    const int t = threadIdx.x, lane = t & 63, wv = t >> 6;
    const int l16 = lane & 15, lq = lane >> 4;
    const int wm = wv >> 1, wn = wv & 1;

    const int srow = lane >> 2, scol = (lane & 3) << 3;
    const unsigned short* gA0 = A + (size_t)(m0 + (wv << 4) + srow) * ldk + kb + scol;
    const unsigned short* gA1 = gA0 + (size_t)64 * ldk;
    const unsigned short* gB0 = Bt + (size_t)(n0 + (wv << 4) + srow) * ldk + kb + scol;
    const unsigned short* gB1 = gB0 + (size_t)64 * ldk;
    unsigned short* lA0 = &As[0][wv << 9];
    unsigned short* lA1 = &As[0][(wv + 4) << 9];
    unsigned short* lB0 = &Bs[0][wv << 9];
    unsigned short* lB1 = &Bs[0][(wv + 4) << 9];

    f32x4 acc[4][4];
#pragma unroll
    for (int i = 0; i < 4; ++i)
#pragma unroll
        for (int j = 0; j < 4; ++j) acc[i][j] = (f32x4){0.f, 0.f, 0.f, 0.f};

    const int NS = (ke - kb) >> 5;
    gload16(gA0, lA0); gload16(gA1, lA1);
    gload16(gB0, lB0); gload16(gB1, lB1);

    for (int s = 0; s < NS; ++s) {
        __syncthreads();
        if (s + 1 < NS) {
            const int nb = (s + 1) & 1, ko = (s + 1) << 5;
            gload16(gA0 + ko, lA0 + (nb << 12)); gload16(gA1 + ko, lA1 + (nb << 12));
            gload16(gB0 + ko, lB0 + (nb << 12)); gload16(gB1 + ko, lB1 + (nb << 12));
        }
        const unsigned short* ab = As[s & 1];
        const unsigned short* bb = Bs[s & 1];
        bf16x8 af[4], bfv[4];
#pragma unroll
        for (int i = 0; i < 4; ++i)
            af[i] = *(const bf16x8*)(ab + (((wm << 6) + (i << 4) + l16) << 5) + (lq << 3));
#pragma unroll
        for (int i = 0; i < 4; ++i)
            bfv[i] = *(const bf16x8*)(bb + (((wn << 6) + (i << 4) + l16) << 5) + (lq << 3));
#pragma unroll
        for (int mf = 0; mf < 4; ++mf)
#pragma unroll
            for (int nf = 0; nf < 4; ++nf)
                acc[mf][nf] = __builtin_amdgcn_mfma_f32_16x16x32_bf16(af[mf], bfv[nf], acc[mf][nf], 0, 0, 0);
    }

    if (EPI == 1) {
#pragma unroll
        for (int mf = 0; mf < 4; ++mf) {
#pragma unroll
            for (int r = 0; r < 4; ++r) {
                int gr = m0 + (wm << 6) + (mf << 4) + (lq << 2) + r;
                const float* rbp = rb + (size_t)(gr / rpb) * 1024;
                float s = 0.0f;
#pragma unroll
                for (int nf = 0; nf < 4; ++nf) {
                    int gc = n0 + (wn << 6) + (nf << 4) + l16;
                    float xv = acc[mf][nf][r] + rbp[gc] + cb1[gc];
                    if (cb2) xv += cb2[gc];
                    s += ftanh(xv) * vvec[gc];
                }
#pragma unroll
                for (int msk = 1; msk < 16; msk <<= 1) s += __shfl_xor(s, msk, 64);
                if (l16 == 0) atomicAdd(&out[gr], s);
            }
        }
    } else {
#pragma unroll
        for (int mf = 0; mf < 4; ++mf) {
            int gr0 = m0 + (wm << 6) + (mf << 4) + (lq << 2);
#pragma unroll
            for (int nf = 0; nf < 4; ++nf) {
                int gc = n0 + (wn << 6) + (nf << 4) + l16;
#pragma unroll
                for (int r = 0; r < 4; ++r)
                    atomicAdd(&out[(size_t)(gr0 + r) * ldc + gc], acc[mf][nf][r]);
            }
        }
    }
}

// gene logits body: A = hnew bf16 (gload_lds), B = W_out f32 KxN (reg-stage
// cvt), full K=1024, plain store with fused bias.
__device__ __forceinline__ void gene_body(
    const unsigned short* __restrict__ hnb, const float* __restrict__ Wout,
    const float* __restrict__ b_out, float* __restrict__ out, int n0)
{
    __shared__ unsigned short As[2][4096];
    __shared__ unsigned short Bs[2][4096];
    const int t = threadIdx.x, lane = t & 63, wv = t >> 6;
    const int l16 = lane & 15, lq = lane >> 4;
    const int wm = wv >> 1, wn = wv & 1;

    const int srow = lane >> 2, scol = (lane & 3) << 3;
    const unsigned short* gA0 = hnb + (size_t)((wv << 4) + srow) * 1024 + scol;
    const unsigned short* gA1 = gA0 + (size_t)64 * 1024;
    unsigned short* lA0 = &As[0][wv << 9];
    unsigned short* lA1 = &As[0][(wv + 4) << 9];

    const int bn = t & 127, kh = t >> 7;
    const bool ok = (n0 + bn) < 40000;
    const float* gB = Wout + (size_t)(kh * 16) * 40000 + (n0 + bn);

    f32x4 acc[4][4];
#pragma unroll
    for (int i = 0; i < 4; ++i)
#pragma unroll
        for (int j = 0; j < 4; ++j) acc[i][j] = (f32x4){0.f, 0.f, 0.f, 0.f};

    auto stageB = [&](int buf, int ko) {
        const float* src = gB + (size_t)ko * 40000;
        float f[16];
#pragma unroll
        for (int j = 0; j < 16; ++j) f[j] = ok ? src[(size_t)j * 40000] : 0.0f;
        u32x4* d = (u32x4*)&Bs[buf][bn * 32 + kh * 16];
        d[0] = (u32x4){pack2(f[0],f[1]), pack2(f[2],f[3]), pack2(f[4],f[5]), pack2(f[6],f[7])};
        d[1] = (u32x4){pack2(f[8],f[9]), pack2(f[10],f[11]), pack2(f[12],f[13]), pack2(f[14],f[15])};
    };

    gload16(gA0, lA0); gload16(gA1, lA1); stageB(0, 0);
    for (int s = 0; s < 32; ++s) {
        __syncthreads();
        if (s + 1 < 32) {
            const int nb = (s + 1) & 1, ko = (s + 1) << 5;
            gload16(gA0 + ko, lA0 + (nb << 12)); gload16(gA1 + ko, lA1 + (nb << 12));
            stageB(nb, ko);
        }
        const unsigned short* ab = As[s & 1];
        const unsigned short* bb = Bs[s & 1];
        bf16x8 af[4], bfv[4];
#pragma unroll
        for (int i = 0; i < 4; ++i)
            af[i] = *(const bf16x8*)(ab + (((wm << 6) + (i << 4) + l16) << 5) + (lq << 3));
#pragma unroll
        for (int i = 0; i < 4; ++i)
            bfv[i] = *(const bf16x8*)(bb + (((wn << 6) + (i << 4) + l16) << 5) + (lq << 3));
#pragma unroll
        for (int mf = 0; mf < 4; ++mf)
#pragma unroll
            for (int nf = 0; nf < 4; ++nf)
                acc[mf][nf] = __builtin_amdgcn_mfma_f32_16x16x32_bf16(af[mf], bfv[nf], acc[mf][nf], 0, 0, 0);
    }
#pragma unroll
    for (int mf = 0; mf < 4; ++mf) {
        int gr0 = (wm << 6) + (mf << 4) + (lq << 2);
#pragma unroll
        for (int nf = 0; nf < 4; ++nf) {
            int gc = n0 + (wn << 6) + (nf << 4) + l16;
            if (gc < 40000) {
                float bo = b_out[gc];
#pragma unroll
                for (int r = 0; r < 4; ++r)
                    out[(size_t)(gr0 + r) * 40000 + gc] = acc[mf][nf][r] + bo;
            }
        }
    }
}

// ------------------------------ GEMM wrappers ------------------------------
__global__ __launch_bounds__(256) void k_stac3(
    const unsigned short* se, const unsigned short* ae, const unsigned short* WmscT,
    const float* tagrow, const float* qsc, const float* bq_sc, const float* v_sc,
    float* stlg, float* aclg) {
    if (blockIdx.z == 0)
        mgemm<1>(se, WmscT, stlg, qsc, bq_sc, nullptr, v_sc, blockIdx.y * 128, blockIdx.x * 128, 0, 1024, 1024, 0, 10);
    else
        mgemm<1>(ae, WmscT, aclg, qsc, bq_sc, tagrow, v_sc, blockIdx.y * 128, blockIdx.x * 128, 0, 1024, 1024, 0, 10);
}

__global__ __launch_bounds__(256) void k_qh4(
    const unsigned short* q0, const unsigned short* W0, const unsigned short* W1,
    const unsigned short* W2, float* o0, float* o1, float* o2) {
    const unsigned short* W = W0; float* o = o0;
    if (blockIdx.z == 1) { W = W1; o = o1; }
    if (blockIdx.z == 2) { W = W2; o = o2; }
    int kb = blockIdx.y << 8;
    mgemm<2>(q0, W, o, nullptr, nullptr, nullptr, nullptr, 0, blockIdx.x * 128, kb, kb + 256, 1024, 1024, 1);
}

__global__ __launch_bounds__(256) void k_gigh2(
    const unsigned short* xb, const unsigned short* q0,
    const unsigned short* Wih, const unsigned short* Whh, float* gi, float* gh) {
    if (blockIdx.z == 0) {
        int kb = blockIdx.y << 9;
        mgemm<2>(xb, Wih, gi, nullptr, nullptr, nullptr, nullptr, 0, blockIdx.x * 128, kb, kb + 512, 4096, 3072, 1);
    } else {
        if (blockIdx.y >= 2) return;
        int kb = blockIdx.y << 9;
        mgemm<2>(q0, Whh, gh, nullptr, nullptr, nullptr, nullptr, 0, blockIdx.x * 128, kb, kb + 512, 1024, 3072, 1);
    }
}

// qsc (16 blocks, split-K 2) + gene logits (313 blocks) in one launch
__global__ __launch_bounds__(256) void k_qsc_gene(
    const unsigned short* hnb, const unsigned short* WqscT, float* qsc,
    const float* Wout, const float* b_out, float* out) {
    int id = blockIdx.x;
    if (id < 16) {
        int x = id & 7, kb = (id >> 3) << 9;
        mgemm<2>(hnb, WqscT, qsc, nullptr, nullptr, nullptr, nullptr, 0, x * 128, kb, kb + 512, 1024, 1024, 1);
    } else {
        gene_body(hnb, Wout, b_out, out, (id - 16) << 7);
    }
}

// --------------------------- prep kernels -----------------------------------
struct CvtArgs { const float* s[6]; unsigned short* d[6]; int pre[7]; };
__global__ __launch_bounds__(256) void k_cvt_all(CvtArgs a) {
    int total = a.pre[6];
    for (int i = blockIdx.x * 256 + threadIdx.x; i < total; i += gridDim.x * 256) {
        int seg = 0;
        while (i >= a.pre[seg + 1]) ++seg;
        int loc = i - a.pre[seg];
        const f32x4* s4 = (const f32x4*)a.s[seg] + (size_t)loc * 2;
        f32x4 q0 = s4[0], q1 = s4[1];
        ((u32x4*)a.d[seg])[loc] =
            (u32x4){pack2(q0[0],q0[1]), pack2(q0[2],q0[3]), pack2(q1[0],q1[1]), pack2(q1[2],q1[3])};
    }
}

struct TrArgs { const float* s[8]; unsigned short* d[8]; };
__global__ __launch_bounds__(256) void k_trcvt(TrArgs a) {
    __shared__ float tile[64][65];
    const float* in = a.s[blockIdx.z];
    unsigned short* ot = a.d[blockIdx.z];
    int k0 = blockIdx.y << 6, n0 = blockIdx.x << 6;
    int tr = threadIdx.x >> 6, tc = threadIdx.x & 63;
#pragma unroll
    for (int i = 0; i < 16; ++i) {
        int r = (i << 2) + tr;
        tile[r][tc] = in[(size_t)(k0 + r) * 1024 + n0 + tc];
    }
    __syncthreads();
#pragma unroll
    for (int i = 0; i < 16; ++i) {
        int r = (i << 2) + tr;
        ot[(size_t)(n0 + r) * 1024 + k0 + tc] = (unsigned short)rne_bf16(tile[tc][r]);
    }
}

// --------------------------- non-GEMM kernels ------------------------------
__device__ __forceinline__ void softmax10(const float* src, float* dst) {
    float m = src[0];
    for (int i = 1; i < 10; ++i) m = fmaxf(m, src[i]);
    float z = 0.f, e[10];
    for (int i = 0; i < 10; ++i) { e[i] = expf(src[i] - m); z += e[i]; }
    float iz = 1.0f / z;
    for (int i = 0; i < 10; ++i) dst[i] = e[i] * iz;
}

// hist softmax + c_his, inp copy, state/action softmax + contexts -> x (bf16)
__global__ __launch_bounds__(256) void k_ctx(
    const float* __restrict__ scores, const int* __restrict__ lens,
    const unsigned short* __restrict__ hs,
    const float* __restrict__ inp, const float* __restrict__ st_sc, const float* __restrict__ ac_sc,
    const unsigned short* __restrict__ se, const unsigned short* __restrict__ ae,
    unsigned short* __restrict__ xb) {
    int b = blockIdx.x, t = threadIdx.x;
    __shared__ float w[256];
    __shared__ float red[256];
    __shared__ float sw[10], aw[10];
    int len = lens[b];
    float s = scores[b * 256 + t];
    bool valid = t < len;
    red[t] = valid ? s : -3.0e38f;
    __syncthreads();
    for (int st = 128; st > 0; st >>= 1) { if (t < st) red[t] = fmaxf(red[t], red[t + st]); __syncthreads(); }
    float m = red[0];
    __syncthreads();
    float e = valid ? expf(s - m) : 0.0f;
    red[t] = e;
    __syncthreads();
    for (int st = 128; st > 0; st >>= 1) { if (t < st) red[t] += red[t + st]; __syncthreads(); }
    float Z = red[0];
    __syncthreads();
    w[t] = e / Z;
    if (t == 0) softmax10(st_sc + b * 10, sw);
    if (t == 64) softmax10(ac_sc + b * 10, aw);
    f32x4 iv = ((const f32x4*)(inp + (size_t)b * 1024))[t];
    *((u32x2*)(xb + (size_t)b * 4096) + t) = (u32x2){pack2(iv[0], iv[1]), pack2(iv[2], iv[3])};
    __syncthreads();
    float a0 = 0.f, a1 = 0.f, a2 = 0.f, a3 = 0.f;
    for (int l = 0; l < 256; ++l) {
        float wl = w[l];
        if (wl == 0.0f) continue;
        u32x2 u = *((const u32x2*)(hs + ((size_t)b * 256 + l) * 1024) + t);
        a0 += wl * bf2f(u[0]); a1 += wl * bf2f(u[0] >> 16);
        a2 += wl * bf2f(u[1]); a3 += wl * bf2f(u[1] >> 16);
    }
    *((u32x2*)(xb + (size_t)b * 4096 + 1024) + t) = (u32x2){pack2(a0, a1), pack2(a2, a3)};
    float cs0=0,cs1=0,cs2=0,cs3=0, ca0=0,ca1=0,ca2=0,ca3=0;
#pragma unroll
    for (int q = 0; q < 10; ++q) {
        u32x2 us = *((const u32x2*)(se + ((size_t)b * 10 + q) * 1024) + t);
        u32x2 ua = *((const u32x2*)(ae + ((size_t)b * 10 + q) * 1024) + t);
        float ws = sw[q], wa = aw[q];
        cs0 += ws * bf2f(us[0]); cs1 += ws * bf2f(us[0] >> 16);
        cs2 += ws * bf2f(us[1]); cs3 += ws * bf2f(us[1] >> 16);
        ca0 += wa * bf2f(ua[0]); ca1 += wa * bf2f(ua[0] >> 16);
        ca2 += wa * bf2f(ua[1]); ca3 += wa * bf2f(ua[1] >> 16);
    }
    *((u32x2*)(xb + (size_t)b * 4096 + 2048) + t) = (u32x2){pack2(cs0, cs1), pack2(cs2, cs3)};
    *((u32x2*)(xb + (size_t)b * 4096 + 3072) + t) = (u32x2){pack2(ca0, ca1), pack2(ca2, ca3)};
}

// GRU elementwise + hs_logits (h_new . hs_vectors) fused; one block per b
__global__ __launch_bounds__(1024) void k_gruhsl(
    const float* __restrict__ gi, const float* __restrict__ gh,
    const float* __restrict__ b_ih, const float* __restrict__ b_hh,
    const float* __restrict__ h0, float* __restrict__ hnew,
    unsigned short* __restrict__ hnb,
    const unsigned short* __restrict__ hs, float* __restrict__ hsl) {
    int b = blockIdx.x, j = threadIdx.x;
    size_t i = (size_t)b * 1024 + j;
    const float* gib = gi + (size_t)b * 3072;
    const float* ghb = gh + (size_t)b * 3072;
    float r = sigm(gib[j] + b_ih[j] + ghb[j] + b_hh[j]);
    float z = sigm(gib[1024 + j] + b_ih[1024 + j] + ghb[1024 + j] + b_hh[1024 + j]);
    float hn = ghb[2048 + j] + b_hh[2048 + j];
    float n = tanhf(gib[2048 + j] + b_ih[2048 + j] + r * hn);
    float h = (1.0f - z) * n + z * h0[i];
    hnew[i] = h;
    hnb[i] = (unsigned short)rne_bf16(h);
    __shared__ float hsm[1024];
    hsm[j] = h;
    __syncthreads();
    int wave = j >> 6, lane = j & 63;
    float hr[16];
#pragma unroll
    for (int k = 0; k < 16; ++k) hr[k] = hsm[lane * 16 + k];
    for (int l = wave; l < 256; l += 16) {
        const u32x4* row = (const u32x4*)(hs + ((size_t)b * 256 + l) * 1024);
        u32x4 u0 = row[lane * 2], u1 = row[lane * 2 + 1];
        float s = hr[0]*bf2f(u0[0]) + hr[1]*bf2f(u0[0]>>16) + hr[2]*bf2f(u0[1]) + hr[3]*bf2f(u0[1]>>16)
                + hr[4]*bf2f(u0[2]) + hr[5]*bf2f(u0[2]>>16) + hr[6]*bf2f(u0[3]) + hr[7]*bf2f(u0[3]>>16)
                + hr[8]*bf2f(u1[0]) + hr[9]*bf2f(u1[0]>>16) + hr[10]*bf2f(u1[1]) + hr[11]*bf2f(u1[1]>>16)
                + hr[12]*bf2f(u1[2]) + hr[13]*bf2f(u1[2]>>16) + hr[14]*bf2f(u1[3]) + hr[15]*bf2f(u1[3]>>16);
#pragma unroll
        for (int msk = 1; msk < 64; msk <<= 1) s += __shfl_xor(s, msk, 64);
        if (lane == 0) hsl[b * 256 + l] = s;
    }
}

// softmax stats over concat + copy_p scatter; one block per b
__global__ __launch_bounds__(256) void k_smsc(
    const float* __restrict__ gene, const float* __restrict__ hsl,
    const float* __restrict__ stl, const float* __restrict__ acl,
    const int* __restrict__ hwi,
    float* __restrict__ mbuf, float* __restrict__ zbuf, float* __restrict__ copyp) {
    int b = blockIdx.x, t = threadIdx.x;
    __shared__ float red[256];
    const f32x4* g4 = (const f32x4*)(gene + (size_t)b * 40000);
    float mx = -3.0e38f;
    for (int i = t; i < 10000; i += 256) {
        f32x4 q = g4[i];
        mx = fmaxf(mx, fmaxf(fmaxf(q[0], q[1]), fmaxf(q[2], q[3])));
    }
    float hv = hsl[b * 256 + t];
    mx = fmaxf(mx, hv);
    if (t < 10) mx = fmaxf(mx, fmaxf(stl[b * 10 + t], acl[b * 10 + t]));
    red[t] = mx; __syncthreads();
    for (int s = 128; s > 0; s >>= 1) { if (t < s) red[t] = fmaxf(red[t], red[t + s]); __syncthreads(); }
    float m = red[0];
    __syncthreads();
    float sum = 0.f;
    for (int i = t; i < 10000; i += 256) {
        f32x4 q = g4[i];
        sum += expf(q[0]-m) + expf(q[1]-m) + expf(q[2]-m) + expf(q[3]-m);
    }
    sum += expf(hv - m);
    if (t < 10) sum += expf(stl[b * 10 + t] - m) + expf(acl[b * 10 + t] - m);
    red[t] = sum; __syncthreads();
    for (int s = 128; s > 0; s >>= 1) { if (t < s) red[t] += red[t + s]; __syncthreads(); }
    float Z = red[0];
    if (t == 0) { mbuf[b] = m; zbuf[b] = Z; }
    float wv = expf(hv - m) / Z;
    atomicAdd(copyp + (size_t)b * 40000 + hwi[b * 256 + t], wv);
}

__global__ __launch_bounds__(256) void k_final(
    float* __restrict__ gene_out, const float* __restrict__ copyp,
    const float* __restrict__ sprob, const float* __restrict__ aprob,
    const float* __restrict__ stl, const float* __restrict__ acl,
    const float* __restrict__ mbuf, const float* __restrict__ zbuf) {
    int b = blockIdx.y, t = threadIdx.x;
    __shared__ float sw[10], aw[10];
    float m = mbuf[b], iz = 1.0f / zbuf[b];
    if (t < 10) sw[t] = expf(stl[b * 10 + t] - m) * iz;
    if (t >= 64 && t < 74) aw[t - 64] = expf(acl[b * 10 + (t - 64)] - m) * iz;
    __syncthreads();
    int v4 = blockIdx.x * 256 + t;
    if (v4 < 10000) {
        size_t base = (size_t)b * 10000 + v4;
        f32x4 g = ((const f32x4*)gene_out)[base];
        f32x4 c = ((const f32x4*)copyp)[base];
        f32x4 acc;
#pragma unroll
        for (int j = 0; j < 4; ++j) acc[j] = expf(g[j] - m) * iz + c[j];
#pragma unroll
        for (int s = 0; s < 10; ++s) {
            f32x4 pv = ((const f32x4*)sprob)[((size_t)b * 10 + s) * 10000 + v4];
            f32x4 av = ((const f32x4*)aprob)[((size_t)b * 10 + s) * 10000 + v4];
            float ws = sw[s], wa = aw[s];
#pragma unroll
            for (int j = 0; j < 4; ++j) acc[j] += ws * pv[j] + wa * av[j];
        }
        f32x4 r;
#pragma unroll
        for (int j = 0; j < 4; ++j) r[j] = logf(acc[j]);
        ((f32x4*)gene_out)[base] = r;
    }
}

// ------------------------------- launcher ----------------------------------
// float ws region (floats)
#define OFF_QH_H  0
#define OFF_QH_S  131072
#define OFF_QH_A  262144
#define OFF_QSC   393216
#define OFF_GI    524288
#define OFF_GH    917504
#define OFF_HSC   1310720
#define OFF_STSC  1343488
#define OFF_ACSC  1344768
#define OFF_STLG  1346048
#define OFF_ACLG  1347328
#define OFF_CTR   1348608
#define ZERO_FLOATS 1348736
#define OFF_HSL   1348736
#define OFF_M     1381504
#define OFF_Z     1381632
#define OFF_COPY  1381760
#define FLOAT_TOTAL 6501760
// short region (shorts, offset from short base)
#define SO_HS     0
#define SO_SE     33554432
#define SO_AE     34865152
#define SO_Q0     36175872
#define SO_X      36306944
#define SO_HNB    36831232
#define SO_WQHT   36962304
#define SO_WQST   38010880
#define SO_WQAT   39059456
#define SO_WQSCT  40108032
#define SO_WMHT   41156608
#define SO_WMST   42205184
#define SO_WMAT   43253760
#define SO_WMSCT  44302336
#define SO_WIH    45350912
#define SO_WHH    57933824

extern "C" void kernel_launch(void* const* d_in, const int* in_sizes, int n_in,
                              void* d_out, int out_size, void* d_ws, size_t ws_size,
                              hipStream_t stream) {
    const float* inp     = (const float*)d_in[0];
    const float* hidden  = (const float*)d_in[1];
    const float* hs      = (const float*)d_in[2];
    const float* sprob   = (const float*)d_in[3];
    const float* se      = (const float*)d_in[4];
    const float* aprob   = (const float*)d_in[5];
    const float* ae      = (const float*)d_in[6];
    const int*   lens    = (const int*)d_in[7];
    const int*   hwi     = (const int*)d_in[8];
    const float* Wq_hist = (const float*)d_in[9];
    const float* bq_hist = (const float*)d_in[10];
    const float* Wm_hist = (const float*)d_in[11];
    const float* v_hist  = (const float*)d_in[12];
    const float* Wq_s    = (const float*)d_in[13];
    const float* bq_s    = (const float*)d_in[14];
    const float* Wm_s    = (const float*)d_in[15];
    const float* v_s     = (const float*)d_in[16];
    const float* Wq_a    = (const float*)d_in[17];
    const float* bq_a    = (const float*)d_in[18];
    const float* Wm_a    = (const float*)d_in[19];
    const float* v_a     = (const float*)d_in[20];
    const float* Wq_sc   = (const float*)d_in[21];
    const float* bq_sc   = (const float*)d_in[22];
    const float* Wm_sc   = (const float*)d_in[23];
    const float* v_sc    = (const float*)d_in[24];
    const float* W_ih    = (const float*)d_in[25];
    const float* W_hh    = (const float*)d_in[26];
    const float* b_ih    = (const float*)d_in[27];
    const float* b_hh    = (const float*)d_in[28];
    const float* W_out   = (const float*)d_in[29];
    const float* b_out   = (const float*)d_in[30];

    float* out  = (float*)d_out;
    float* w    = (float*)d_ws;
    float* hnew = out + BV;
    unsigned short* sb = (unsigned short*)(w + FLOAT_TOTAL);

    float* qh_h = w + OFF_QH_H;  float* qh_s = w + OFF_QH_S;  float* qh_a = w + OFF_QH_A;
    float* qsc  = w + OFF_QSC;   float* gi   = w + OFF_GI;    float* gh   = w + OFF_GH;
    float* hsc  = w + OFF_HSC;   float* stsc = w + OFF_STSC;  float* acsc = w + OFF_ACSC;
    float* stlg = w + OFF_STLG;  float* aclg = w + OFF_ACLG;
    float* hsl  = w + OFF_HSL;   float* mbuf = w + OFF_M;     float* zbuf = w + OFF_Z;
    float* copyp = w + OFF_COPY;
    int*   ctr  = (int*)(w + OFF_CTR);

    unsigned short* hs_bf = sb + SO_HS;   unsigned short* se_bf = sb + SO_SE;
    unsigned short* ae_bf = sb + SO_AE;   unsigned short* q0_bf = sb + SO_Q0;
    unsigned short* x_bf  = sb + SO_X;    unsigned short* hnb   = sb + SO_HNB;
    unsigned short* WqhT  = sb + SO_WQHT; unsigned short* WqsT  = sb + SO_WQST;
    unsigned short* WqaT  = sb + SO_WQAT; unsigned short* WqscT = sb + SO_WQSCT;
    unsigned short* WmhT  = sb + SO_WMHT; unsigned short* WmsT  = sb + SO_WMST;
    unsigned short* WmaT  = sb + SO_WMAT; unsigned short* WmscT = sb + SO_WMSCT;
    unsigned short* WihB  = sb + SO_WIH;  unsigned short* WhhB  = sb + SO_WHH;

    dim3 blk(256);

    hipMemsetAsync(w, 0, (size_t)ZERO_FLOATS * 4, stream);
    hipMemsetAsync(copyp, 0, (size_t)BV * 4, stream);

    // bf16 conversions (one kernel)
    CvtArgs ca;
    ca.s[0]=hs; ca.s[1]=se; ca.s[2]=ae; ca.s[3]=hidden; ca.s[4]=W_ih; ca.s[5]=W_hh;
    ca.d[0]=hs_bf; ca.d[1]=se_bf; ca.d[2]=ae_bf; ca.d[3]=q0_bf; ca.d[4]=WihB; ca.d[5]=WhhB;
    ca.pre[0]=0; ca.pre[1]=4194304; ca.pre[2]=4358144; ca.pre[3]=4521984;
    ca.pre[4]=4538368; ca.pre[5]=6111232; ca.pre[6]=6504448;
    k_cvt_all<<<dim3(4096), blk, 0, stream>>>(ca);

    TrArgs ta;
    ta.s[0]=Wq_hist; ta.s[1]=Wq_s; ta.s[2]=Wq_a; ta.s[3]=Wq_sc;
    ta.s[4]=Wm_hist; ta.s[5]=Wm_s; ta.s[6]=Wm_a; ta.s[7]=Wm_sc;
    ta.d[0]=WqhT; ta.d[1]=WqsT; ta.d[2]=WqaT; ta.d[3]=WqscT;
    ta.d[4]=WmhT; ta.d[5]=WmsT; ta.d[6]=WmaT; ta.d[7]=WmscT;
    k_trcvt<<<dim3(16, 16, 8), blk, 0, stream>>>(ta);

    // q-projections (split-K atomic, bias folded into consumers)
    k_qh4<<<dim3(8, 4, 3), blk, 0, stream>>>(q0_bf, WqhT, WqsT, WqaT, qh_h, qh_s, qh_a);

    // big hist MLP + state/action score MLPs: persistent dynamic-queue GEMM
    BigArgs ba;
    ba.hs = hs_bf; ba.WmhT = WmhT; ba.se = se_bf; ba.ae = ae_bf;
    ba.WmsT = WmsT; ba.WmaT = WmaT; ba.lens = lens;
    ba.qh_h = qh_h; ba.bq_h = bq_hist; ba.v_h = v_hist;
    ba.qh_s = qh_s; ba.bq_s = bq_s; ba.v_s = v_s;
    ba.qh_a = qh_a; ba.bq_a = bq_a; ba.v_a = v_a;
    ba.hsc = hsc; ba.stsc = stsc; ba.acsc = acsc;
    k_big<<<dim3(256), dim3(512), 0, stream>>>(ba, ctr);

    // contexts -> x (bf16)
    k_ctx<<<dim3(128), blk, 0, stream>>>(hsc, lens, hs_bf, inp, stsc, acsc, se_bf, ae_bf, x_bf);
    // GRU gates
    k_gigh2<<<dim3(24, 8, 2), blk, 0, stream>>>(x_bf, q0_bf, WihB, WhhB, gi, gh);
    // GRU elementwise + hs logits
    k_gruhsl<<<dim3(128), dim3(1024), 0, stream>>>(gi, gh, b_ih, b_hh, hidden, hnew, hnb, hs_bf, hsl);
    // copy-scorer query + gene logits (bias fused into store)
    k_qsc_gene<<<dim3(329), blk, 0, stream>>>(hnb, WqscT, qsc, W_out, b_out, out);
    // st / ac logits
    k_stac3<<<dim3(8, 10, 2), blk, 0, stream>>>(se_bf, ae_bf, WmscT, Wm_sc + (size_t)1024 * 1024,
                                                qsc, bq_sc, v_sc, stlg, aclg);
    // softmax stats + scatter, then fused final
    k_smsc<<<dim3(128), blk, 0, stream>>>(out, hsl, stlg, aclg, hwi, mbuf, zbuf, copyp);
    k_final<<<dim3(40, 128), blk, 0, stream>>>(out, copyp, sprob, aprob, stlg, aclg, mbuf, zbuf);

    (void)in_sizes; (void)n_in; (void)out_size; (void)ws_size;
}